// Round 12
// baseline (597.207 us; speedup 1.0000x reference)
//
#include <hip/hip_runtime.h>

// KAN forward: 3 layers of [deg-3 B-spline basis (64 bases) -> einsum 'bik,ijk->bj'].
// Only 4 basis values are nonzero per point => 4-tap gather per (i,j).
//
// NUMERICS (frozen since R6 — absmax sits exactly at threshold; per-(b,j)
// product set and fp64 add order must stay bitwise-identical):
//  * knots: jnp.linspace fp32 semantics, endpoint forced to 1.0f
//  * basis: fp32 Cox-de Boor, reference expression tree, contraction OFF
//  * einsum: fp64 accumulation, per-(b,j) order = i ascending, k ascending
//    (shift-aligned w' slots: +/-0-product adds are bitwise no-ops, R7-R11)
//
// PERF history: R6 1967 -> R7 711 -> R8 636 -> R9 420 -> R10 424 -> R11 404
// (layer2 colgather 183us ~1.45x its 125us L2-BW floor; HIDDEN: layer-3
// row-path was ~140us TA-gather-bound on scattered k0 reads).
// R12: (1) layer 3 -> colgather w/ transposed Ct2 (kills the TA gather;
// Ct2 reuses dead Ct1 slot => tier-A budget unchanged at 41.94MB proven);
// (2) JW=2 j-split for 256-out colgathers => 32 waves/CU latency hiding;
// (3) [b][i] table layout: precomp fully coalesced both sides, broadcast
// table reads walk sequential i.

#define NBATCH 4096

typedef float f4a __attribute__((ext_vector_type(4), aligned(4)));

// jnp.linspace(0,1,68,f32): delta = fl32(1/67); K[m] = fl32(m)*delta; K[67]=1.
__device__ __forceinline__ float knotf(int m) {
    if (m == 67) return 1.0f;
    return (float)m * (1.0f / 67.0f);
}

// Bitwise replica of the reference Cox-de Boor recursion on the 7-wide
// nonzero window around span t.  w[r] = B_{t-3+r,3}(x), r=0..3.
__device__ __forceinline__ void basis4(float xf, int& t_out, float w[4]) {
#pragma clang fp contract(off)
    int t = (int)floorf(xf * 67.0f);
    t = t < 0 ? 0 : (t > 66 ? 66 : t);
    #pragma unroll
    for (int it = 0; it < 2; ++it) {   // enforce K[t] <= x < K[t+1] on fp32 knots
        if (t > 0 && xf < knotf(t)) --t;
        else if (t < 66 && xf >= knotf(t + 1)) ++t;
    }
    float W[7];
    #pragma unroll
    for (int j = 0; j < 7; ++j) W[j] = 0.0f;
    W[3] = 1.0f;   // degree-0 indicator at span t
    #pragma unroll
    for (int d = 1; d <= 3; ++d) {
        #pragma unroll
        for (int j = 0; j <= 6 - d; ++j) {
            const int k = t - 3 + j;
            const float ka = knotf(k);
            const float kb = knotf(k + d);
            const float kc = knotf(k + d + 1);
            const float ke = knotf(k + 1);
            const float lt = ((xf - ka) / (kb - ka)) * W[j];
            const float rt = ((kc - xf) / (kc - ke)) * W[j + 1];
            W[j] = lt + rt;
        }
    }
    t_out = t;
    w[0] = W[0]; w[1] = W[1]; w[2] = W[2]; w[3] = W[3];
}

// Shift-aligned table entry: k0 = clamp(t-3,0,60); w'[m] applies to C[k0+m],
// m-ascending == k-ascending == R6 order; displaced/OOB slots get w'=0.
__device__ __forceinline__ void make_wk(float xf, float4& wv, int& kv) {
    float wp[4] = {0.f, 0.f, 0.f, 0.f};
    int k0 = 0;
    if (xf >= 0.0f && xf < 1.0f) {
        int t; float w[4];
        basis4(xf, t, w);
        k0 = t - 3;
        k0 = k0 < 0 ? 0 : (k0 > 60 ? 60 : k0);
        const int s = (t - 3) - k0;
        #pragma unroll
        for (int m = 0; m < 4; ++m) {
            const int r = m - s;
            wp[m] = (r >= 0 && r <= 3) ? w[r] : 0.0f;
        }
    }
    wv = make_float4(wp[0], wp[1], wp[2], wp[3]);
    kv = k0;
}

// ---------------- tier-A precompute: [b][i] tables, coalesced both sides ----
// act is row-major [b][IN]; gid = b*IN + i indexes act AND tables directly.
__global__ __launch_bounds__(256) void precomp_bi(const float* __restrict__ act,
        float4* __restrict__ wtab, int* __restrict__ ktab, int total) {
    const int gid = blockIdx.x * 256 + threadIdx.x;
    if (gid >= total) return;
    float4 wv; int kv;
    make_wk(act[gid], wv, kv);
    wtab[gid] = wv;
    ktab[gid] = kv;
}

// ---------------- C transpose: C[i][j][k] -> Ct[i][k][j] --------------------
template<int OUT>
__global__ void transpose_nt(const float* __restrict__ C, float* __restrict__ Ct) {
    __shared__ float tile[32][33];
    const int i  = blockIdx.z;
    const int k0 = blockIdx.x * 32;
    const int j0 = blockIdx.y * 32;
    const float* src = C + (size_t)i * OUT * 64;
    #pragma unroll
    for (int r = threadIdx.y; r < 32; r += 8)
        tile[r][threadIdx.x] = src[(size_t)(j0 + r) * 64 + (k0 + threadIdx.x)];
    __syncthreads();
    float* dst = Ct + (size_t)i * 64 * OUT;
    #pragma unroll
    for (int r = threadIdx.y; r < 32; r += 8)
        dst[(size_t)(k0 + r) * OUT + (j0 + threadIdx.x)] = tile[threadIdx.x][r];
}

// ---------------- column-parallel gather ------------------------------------
// Wave = one b x (64*JW j's); lane owns JW consecutive j.  k0/w wave-uniform:
// k0 in SGPR (readfirstlane) => scalar row addressing, broadcast table loads,
// coalesced row loads (JW=2: b64 / JW=1: b32).  Tables [b][IN].
// fp64 chain per (b,j): i ascending, k ascending — bitwise == R6.
template<int JW> struct VecT;
template<> struct VecT<1> { using T = float;  };
template<> struct VecT<2> { using T = float2; };
__device__ __forceinline__ float velem(const float&  v, int)   { return v; }
__device__ __forceinline__ float velem(const float2& v, int e) { return e ? v.y : v.x; }

template<int IN, int OUT, int JW>
__global__ __launch_bounds__(256, 8) void kan_colgather(
        const float* __restrict__ Ct,          // [IN][64][OUT]
        const float4* __restrict__ wtab, const int* __restrict__ ktab,
        float* __restrict__ aout) {            // [4096][OUT]
    using Vec = typename VecT<JW>::T;
    constexpr int NS = OUT / (64 * JW);        // j-segments per b
    const int tid  = threadIdx.x;
    const int lane = tid & 63;
    const int g    = blockIdx.x * 4 + (tid >> 6);
    const int b    = g / NS;
    const int seg  = g % NS;
    const int j0   = seg * (64 * JW) + lane * JW;

    double acc[JW];
    #pragma unroll
    for (int e = 0; e < JW; ++e) acc[e] = 0.0;

    const float4* wt = wtab + (size_t)b * IN;
    const int*    kt = ktab + (size_t)b * IN;

    // table pipeline (distance 2); k wave-uniform in SGPR
    float4 wA = wt[0];
    int    kA = __builtin_amdgcn_readfirstlane(kt[0]);
    float4 wB = wA; int kB = kA;
    if (IN > 1) { wB = wt[1]; kB = __builtin_amdgcn_readfirstlane(kt[1]); }

    // C row pipeline (distance 1): 4 tap rows in flight
    Vec c0, c1, c2, c3;
    {
        const float* base = Ct + (size_t)kA * OUT + j0;
        c0 = *(const Vec*)(base);
        c1 = *(const Vec*)(base + OUT);
        c2 = *(const Vec*)(base + 2 * OUT);
        c3 = *(const Vec*)(base + 3 * OUT);
    }

    for (int i = 0; i < IN; ++i) {
        const int ip1 = (i + 1 < IN) ? i + 1 : IN - 1;
        const int ip2 = (i + 2 < IN) ? i + 2 : IN - 1;
        // prefetch C(i+1) rows via kB
        Vec n0, n1, n2, n3;
        {
            const float* bn = Ct + ((size_t)ip1 * 64 + kB) * OUT + j0;
            n0 = *(const Vec*)(bn);
            n1 = *(const Vec*)(bn + OUT);
            n2 = *(const Vec*)(bn + 2 * OUT);
            n3 = *(const Vec*)(bn + 3 * OUT);
        }
        // prefetch tables (i+2)
        const float4 wC = wt[ip2];
        const int    kC = __builtin_amdgcn_readfirstlane(kt[ip2]);
        // compute current i: per j, taps k-ascending — R6 order
        const double w0 = (double)wA.x, w1 = (double)wA.y;
        const double w2 = (double)wA.z, w3 = (double)wA.w;
        #pragma unroll
        for (int e = 0; e < JW; ++e) {
            acc[e] = fma(w0, (double)velem(c0, e), acc[e]);
            acc[e] = fma(w1, (double)velem(c1, e), acc[e]);
            acc[e] = fma(w2, (double)velem(c2, e), acc[e]);
            acc[e] = fma(w3, (double)velem(c3, e), acc[e]);
        }
        wA = wB; kA = kB; wB = wC; kB = kC;
        c0 = n0; c1 = n1; c2 = n2; c3 = n3;
    }

    Vec o;
    #pragma unroll
    for (int e = 0; e < JW; ++e) {
        float v = (float)acc[e];
        if (JW == 1) *(float*)&o = v; else ((float*)&o)[e] = v;
    }
    *(Vec*)(aout + (size_t)b * OUT + j0) = o;
}

// ---------------- tier B: R9 proven path ([i][b] tables, row gather) --------

__global__ __launch_bounds__(256) void precomp_basis(const float* __restrict__ act,
        int IN, int transposed, float4* __restrict__ wtab, int* __restrict__ ktab,
        int total) {
    int gid = blockIdx.x * 256 + threadIdx.x;
    if (gid >= total) return;
    const int i = gid >> 12;
    const int b = gid & 4095;
    const float xf = transposed ? act[gid] : act[(size_t)b * IN + i];
    float4 wv; int kv;
    make_wk(xf, wv, kv);
    wtab[gid] = wv;
    ktab[gid] = kv;
}

template<int IN, int OUT, int JPT, bool TSTORE>
__global__ __launch_bounds__(256) void kan_direct(const float* __restrict__ Cg,
        const float4* __restrict__ wtab, const int* __restrict__ ktab,
        float* __restrict__ aout) {
    constexpr int JSPAN = 4 * JPT;
    constexpr int NJT = OUT / JSPAN;
    const int bid = blockIdx.x, tid = threadIdx.x;
    const int jt   = bid % NJT;
    const int bblk = bid / NJT;
    const int bl = tid & 63;
    const int jc = tid >> 6;
    const int j0 = jt * JSPAN + jc * JPT;
    const int b  = bblk * 64 + bl;

    double acc[JPT];
    #pragma unroll
    for (int m = 0; m < JPT; ++m) acc[m] = 0.0;

    float4 wv = wtab[b];
    int    kv = ktab[b];
    const float* Crow = Cg + (size_t)j0 * 64;

    for (int i = 0; i < IN; ++i) {
        const float4 wcur = wv;
        const int    kcur = kv;
        if (i + 1 < IN) {
            wv = wtab[(size_t)(i + 1) * 4096 + b];
            kv = ktab[(size_t)(i + 1) * 4096 + b];
        }
        const float* base = Crow + kcur;
        const double w0 = (double)wcur.x, w1 = (double)wcur.y;
        const double w2 = (double)wcur.z, w3 = (double)wcur.w;
        #pragma unroll
        for (int m = 0; m < JPT; ++m) {
            const f4a c = *(const f4a*)(base + m * 64);
            acc[m] = fma(w0, (double)c.x, acc[m]);
            acc[m] = fma(w1, (double)c.y, acc[m]);
            acc[m] = fma(w2, (double)c.z, acc[m]);
            acc[m] = fma(w3, (double)c.w, acc[m]);
        }
        Crow += (size_t)OUT * 64;
    }

    if (TSTORE) {
        #pragma unroll
        for (int m = 0; m < JPT; ++m)
            aout[(size_t)(j0 + m) * 4096 + b] = (float)acc[m];
    } else {
        #pragma unroll
        for (int m = 0; m < JPT; ++m)
            aout[(size_t)b * OUT + j0 + m] = (float)acc[m];
    }
}

// ---------------- tier C: R6 monolithic (zero workspace, proven) ------------

__device__ __forceinline__ void stage1(float xf, float sw[4], int& st) {
    const bool inr = (xf >= 0.0f) && (xf < 1.0f);
    if (!inr) { st = -1; sw[0] = sw[1] = sw[2] = sw[3] = 0.0f; return; }
    int t; float w[4];
    basis4(xf, t, w);
    sw[0] = w[0]; sw[1] = w[1]; sw[2] = w[2]; sw[3] = w[3];
    st = t;
}

template<int IN, int OUT>
__device__ __forceinline__ float gather_acc(const float* __restrict__ C, int j,
                                            const float (*__restrict__ sw)[4],
                                            const int* __restrict__ st) {
    double acc = 0.0;
    for (int i = 0; i < IN; ++i) {
        const int t = st[i];
        if (t < 0) continue;
        const float* Crow = C + ((size_t)i * OUT + j) * 64;
        #pragma unroll
        for (int r = 0; r < 4; ++r) {
            const int k4 = t - 3 + r;
            if (k4 >= 0 && k4 <= 63)
                acc += (double)sw[i][r] * (double)Crow[k4];
        }
    }
    return (float)acc;
}

__global__ __launch_bounds__(256) void kan_fused(const float* __restrict__ x,
                                                 const float* __restrict__ C0,
                                                 const float* __restrict__ C1,
                                                 const float* __restrict__ C2,
                                                 float* __restrict__ out) {
    __shared__ float cur[256];
    __shared__ float sw[256][4];
    __shared__ int   st[256];
    const int b = blockIdx.x, tid = threadIdx.x;

    if (tid < 64) stage1(x[(size_t)b * 64 + tid], sw[tid], st[tid]);
    __syncthreads();
    {
        const float a = gather_acc<64, 256>(C0, tid, sw, st);
        __syncthreads();
        cur[tid] = a;
    }
    __syncthreads();

    stage1(cur[tid], sw[tid], st[tid]);
    __syncthreads();
    {
        const float a = gather_acc<256, 256>(C1, tid, sw, st);
        __syncthreads();
        cur[tid] = a;
    }
    __syncthreads();

    stage1(cur[tid], sw[tid], st[tid]);
    __syncthreads();
    if (tid < 64) out[(size_t)b * 64 + tid] = gather_acc<256, 64>(C2, tid, sw, st);
}

// ---------------- launcher --------------------------------------------------

extern "C" void kernel_launch(void* const* d_in, const int* in_sizes, int n_in,
                              void* d_out, int out_size, void* d_ws, size_t ws_size,
                              hipStream_t stream) {
    const float* x  = (const float*)d_in[0];   // (4096, 64)
    const float* C0 = (const float*)d_in[1];   // (64, 256, 64)
    const float* C1 = (const float*)d_in[2];   // (256, 256, 64)
    const float* C2 = (const float*)d_in[3];   // (256, 64, 64)
    float* out = (float*)d_out;                // (4096, 64)

    const size_t WTAB = (size_t)4096 * 256 * 16;   // 16.78 MB
    const size_t KTAB = (size_t)4096 * 256 * 4;    //  4.19 MB
    const size_t CT1  = (size_t)256 * 64 * 256 * 4;// 16.78 MB (parks a1, later Ct2)
    const size_t ACT  = (size_t)4096 * 256 * 4;    //  4.19 MB (Ct0, later a2)
    const size_t needA = WTAB + KTAB + CT1 + ACT;  // 41.94 MB == R10/R11-proven
    const size_t needB = WTAB + KTAB + 2 * ACT;    // 29.36 MB (R9 proven)

    if (ws_size >= needA) {
        float4* wA   = (float4*)d_ws;
        int*    kA   = (int*)  ((char*)d_ws + WTAB);
        float*  ct1  = (float*)((char*)d_ws + WTAB + KTAB);       // a1 parks, then Ct1, then Ct2
        float*  actb = (float*)((char*)d_ws + WTAB + KTAB + CT1); // Ct0, then a2
        float*  a1   = ct1;
        float*  ct0  = actb;
        float*  ct2  = ct1;   // Ct2 (4.19 MB) overwrites dead Ct1 after layer 2
        float*  a2   = actb;  // overwrites dead Ct0 after layer 2

        transpose_nt<256><<<dim3(2, 8, 64), dim3(32, 8), 0, stream>>>(C0, ct0);
        precomp_bi<<<1024, 256, 0, stream>>>(x, wA, kA, 64 * 4096);
        kan_colgather<64, 256, 2><<<2048, 256, 0, stream>>>(ct0, wA, kA, a1);
        precomp_bi<<<4096, 256, 0, stream>>>(a1, wA, kA, 256 * 4096);
        transpose_nt<256><<<dim3(2, 8, 256), dim3(32, 8), 0, stream>>>(C1, ct1);
        kan_colgather<256, 256, 2><<<2048, 256, 0, stream>>>(ct1, wA, kA, a2);
        transpose_nt<64><<<dim3(2, 2, 256), dim3(32, 8), 0, stream>>>(C2, ct2);
        precomp_bi<<<4096, 256, 0, stream>>>(a2, wA, kA, 256 * 4096);
        kan_colgather<256, 64, 1><<<1024, 256, 0, stream>>>(ct2, wA, kA, out);
    } else if (ws_size >= needB) {
        float4* wtab = (float4*)d_ws;
        int*    ktab = (int*)((char*)d_ws + WTAB);
        float*  a1T  = (float*)((char*)d_ws + WTAB + KTAB);
        float*  a2T  = a1T + (size_t)4096 * 256;

        precomp_basis<<<1024, 256, 0, stream>>>(x, 64, 0, wtab, ktab, 64 * 4096);
        kan_direct<64, 256, 4, true><<<1024, 256, 0, stream>>>(C0, wtab, ktab, a1T);
        precomp_basis<<<4096, 256, 0, stream>>>(a1T, 256, 1, wtab, ktab, 256 * 4096);
        kan_direct<256, 256, 4, true><<<1024, 256, 0, stream>>>(C1, wtab, ktab, a2T);
        precomp_basis<<<4096, 256, 0, stream>>>(a2T, 256, 1, wtab, ktab, 256 * 4096);
        kan_direct<256, 64, 1, false><<<1024, 256, 0, stream>>>(C2, wtab, ktab, out);
    } else {
        kan_fused<<<NBATCH, 256, 0, stream>>>(x, C0, C1, C2, out);
    }
}

// Round 13
// 408.080 us; speedup vs baseline: 1.4635x; 1.4635x over previous
//
#include <hip/hip_runtime.h>

// KAN forward: 3 layers of [deg-3 B-spline basis (64 bases) -> einsum 'bik,ijk->bj'].
// Only 4 basis values are nonzero per point => 4-tap gather per (i,j).
//
// NUMERICS (frozen since R6 — absmax sits exactly at threshold; per-(b,j)
// product set and fp64 add order must stay bitwise-identical):
//  * knots: jnp.linspace fp32 semantics, endpoint forced to 1.0f
//  * basis: fp32 Cox-de Boor, reference expression tree, contraction OFF
//  * einsum: fp64 accumulation, per-(b,j) order = i ascending, k ascending
//    (shift-aligned w' slots: +/-0-product adds are bitwise no-ops, R7-R12)
//
// PERF history: R6 1967 -> R7 711 -> R8 636 -> R9 420 -> R10 424 -> R11 404
// -> R12 597 REGRESSION (JW=2/1 halved bytes-per-wave-load; delivered L2 BW
// exactly halved: the VMEM path is REQUEST-RATE bound, occupancy is not the
// lever).  R13: revert layers 1-2 to R11 JW=4 geometry (b128 = 1KB/wave
// loads) + distance-2 C-row prefetch; layer 3 = 4b-per-wave colgather on
// Ct2[i][k][j] (1KB/wave in 4x256B segments, tap rows lane-local so the
// sequential fp64 chain is preserved).

#define NBATCH 4096

typedef float f4a __attribute__((ext_vector_type(4), aligned(4)));

// jnp.linspace(0,1,68,f32): delta = fl32(1/67); K[m] = fl32(m)*delta; K[67]=1.
__device__ __forceinline__ float knotf(int m) {
    if (m == 67) return 1.0f;
    return (float)m * (1.0f / 67.0f);
}

// Bitwise replica of the reference Cox-de Boor recursion on the 7-wide
// nonzero window around span t.  w[r] = B_{t-3+r,3}(x), r=0..3.
__device__ __forceinline__ void basis4(float xf, int& t_out, float w[4]) {
#pragma clang fp contract(off)
    int t = (int)floorf(xf * 67.0f);
    t = t < 0 ? 0 : (t > 66 ? 66 : t);
    #pragma unroll
    for (int it = 0; it < 2; ++it) {   // enforce K[t] <= x < K[t+1] on fp32 knots
        if (t > 0 && xf < knotf(t)) --t;
        else if (t < 66 && xf >= knotf(t + 1)) ++t;
    }
    float W[7];
    #pragma unroll
    for (int j = 0; j < 7; ++j) W[j] = 0.0f;
    W[3] = 1.0f;   // degree-0 indicator at span t
    #pragma unroll
    for (int d = 1; d <= 3; ++d) {
        #pragma unroll
        for (int j = 0; j <= 6 - d; ++j) {
            const int k = t - 3 + j;
            const float ka = knotf(k);
            const float kb = knotf(k + d);
            const float kc = knotf(k + d + 1);
            const float ke = knotf(k + 1);
            const float lt = ((xf - ka) / (kb - ka)) * W[j];
            const float rt = ((kc - xf) / (kc - ke)) * W[j + 1];
            W[j] = lt + rt;
        }
    }
    t_out = t;
    w[0] = W[0]; w[1] = W[1]; w[2] = W[2]; w[3] = W[3];
}

// Shift-aligned table entry: k0 = clamp(t-3,0,60); w'[m] applies to C[k0+m],
// m-ascending == k-ascending == R6 order; displaced/OOB slots get w'=0.
__device__ __forceinline__ void make_wk(float xf, float4& wv, int& kv) {
    float wp[4] = {0.f, 0.f, 0.f, 0.f};
    int k0 = 0;
    if (xf >= 0.0f && xf < 1.0f) {
        int t; float w[4];
        basis4(xf, t, w);
        k0 = t - 3;
        k0 = k0 < 0 ? 0 : (k0 > 60 ? 60 : k0);
        const int s = (t - 3) - k0;
        #pragma unroll
        for (int m = 0; m < 4; ++m) {
            const int r = m - s;
            wp[m] = (r >= 0 && r <= 3) ? w[r] : 0.0f;
        }
    }
    wv = make_float4(wp[0], wp[1], wp[2], wp[3]);
    kv = k0;
}

// ---------------- tier-A precompute: [b][i] tables, coalesced both sides ----
__global__ __launch_bounds__(256) void precomp_bi(const float* __restrict__ act,
        float4* __restrict__ wtab, int* __restrict__ ktab, int total) {
    const int gid = blockIdx.x * 256 + threadIdx.x;
    if (gid >= total) return;
    float4 wv; int kv;
    make_wk(act[gid], wv, kv);
    wtab[gid] = wv;
    ktab[gid] = kv;
}

// ---------------- C transpose: C[i][j][k] -> Ct[i][k][j] --------------------
template<int OUT>
__global__ void transpose_nt(const float* __restrict__ C, float* __restrict__ Ct) {
    __shared__ float tile[32][33];
    const int i  = blockIdx.z;
    const int k0 = blockIdx.x * 32;
    const int j0 = blockIdx.y * 32;
    const float* src = C + (size_t)i * OUT * 64;
    #pragma unroll
    for (int r = threadIdx.y; r < 32; r += 8)
        tile[r][threadIdx.x] = src[(size_t)(j0 + r) * 64 + (k0 + threadIdx.x)];
    __syncthreads();
    float* dst = Ct + (size_t)i * 64 * OUT;
    #pragma unroll
    for (int r = threadIdx.y; r < 32; r += 8)
        dst[(size_t)(k0 + r) * OUT + (j0 + threadIdx.x)] = tile[threadIdx.x][r];
}

// ---------------- column-parallel gather, OUT=256 (layers 1-2) --------------
// Wave = one b; lane owns j-quad [4*lane..4*lane+3] => b128 (1KB/wave) row
// loads.  k0/w wave-uniform (SGPR via readfirstlane).  Distance-2 C prefetch
// (8 f4a in flight), tables at distance 3.  Tables [b][IN].
// fp64 chain per (b,j): i ascending, k ascending — bitwise == R6.
template<int IN, int OUT>
__global__ __launch_bounds__(256, 8) void kan_colgather(
        const float* __restrict__ Ct,          // [IN][64][OUT]
        const float4* __restrict__ wtab, const int* __restrict__ ktab,
        float* __restrict__ aout) {            // [4096][OUT]
    const int tid  = threadIdx.x;
    const int lane = tid & 63;
    const int b    = blockIdx.x * 4 + (tid >> 6);
    const int j0   = lane * 4;

    const float4* wt = wtab + (size_t)b * IN;
    const int*    kt = ktab + (size_t)b * IN;

    double acc[4] = {0.0, 0.0, 0.0, 0.0};

    // tables for i=0,1,2
    float4 wA = wt[0];
    int    kA = __builtin_amdgcn_readfirstlane(kt[0]);
    float4 wB = wA, wC = wA;
    int    kB = kA, kC = kA;
    if (IN > 1) { wB = wt[1]; kB = __builtin_amdgcn_readfirstlane(kt[1]); }
    if (IN > 2) { wC = wt[2]; kC = __builtin_amdgcn_readfirstlane(kt[2]); }

    // C rows for i=0 (cc) and i=1 (cn)
    f4a cc0, cc1, cc2, cc3, cn0, cn1, cn2, cn3;
    {
        const float* p = Ct + (size_t)kA * OUT + j0;
        cc0 = *(const f4a*)(p);           cc1 = *(const f4a*)(p + OUT);
        cc2 = *(const f4a*)(p + 2 * OUT); cc3 = *(const f4a*)(p + 3 * OUT);
    }
    {
        const int i1 = (IN > 1) ? 1 : 0;
        const float* p = Ct + ((size_t)i1 * 64 + kB) * OUT + j0;
        cn0 = *(const f4a*)(p);           cn1 = *(const f4a*)(p + OUT);
        cn2 = *(const f4a*)(p + 2 * OUT); cn3 = *(const f4a*)(p + 3 * OUT);
    }

    for (int i = 0; i < IN; ++i) {
        const int ip2 = (i + 2 < IN) ? i + 2 : IN - 1;
        const int ip3 = (i + 3 < IN) ? i + 3 : IN - 1;
        // issue C(i+2) via kC
        f4a cm0, cm1, cm2, cm3;
        {
            const float* p = Ct + ((size_t)ip2 * 64 + kC) * OUT + j0;
            cm0 = *(const f4a*)(p);           cm1 = *(const f4a*)(p + OUT);
            cm2 = *(const f4a*)(p + 2 * OUT); cm3 = *(const f4a*)(p + 3 * OUT);
        }
        // tables (i+3)
        const float4 wD = wt[ip3];
        const int    kD = __builtin_amdgcn_readfirstlane(kt[ip3]);
        // compute current i: per j, taps k-ascending — R6 order
        const double w0 = (double)wA.x, w1 = (double)wA.y;
        const double w2 = (double)wA.z, w3 = (double)wA.w;
        #pragma unroll
        for (int e = 0; e < 4; ++e) {
            acc[e] = fma(w0, (double)cc0[e], acc[e]);
            acc[e] = fma(w1, (double)cc1[e], acc[e]);
            acc[e] = fma(w2, (double)cc2[e], acc[e]);
            acc[e] = fma(w3, (double)cc3[e], acc[e]);
        }
        // rotate pipelines
        wA = wB; kA = kB; wB = wC; kB = kC; wC = wD; kC = kD;
        cc0 = cn0; cc1 = cn1; cc2 = cn2; cc3 = cn3;
        cn0 = cm0; cn1 = cm1; cn2 = cm2; cn3 = cm3;
    }

    const float4 o = make_float4((float)acc[0], (float)acc[1],
                                 (float)acc[2], (float)acc[3]);
    *(float4*)(aout + (size_t)b * OUT + j0) = o;   // coalesced 1KB/wave
}

// ---------------- column-parallel gather, OUT=64 (layer 3) ------------------
// Wave = 4 b; 16 lanes per b; lane = (bsub = lane>>4, jq = lane&15) owns
// j-quad.  Each wave-load moves 4 x 256B contiguous row segments (1KB, TA-
// mergeable).  Tap rows lane-local => strict i-asc/k-asc fp64 chain kept.
template<int IN>
__global__ __launch_bounds__(256, 8) void kan_colgather4b(
        const float* __restrict__ Ct,          // [IN][64][64]
        const float4* __restrict__ wtab, const int* __restrict__ ktab,
        float* __restrict__ outp) {            // [4096][64]
    const int tid   = threadIdx.x;
    const int lane  = tid & 63;
    const int wvid  = blockIdx.x * 4 + (tid >> 6);   // 0..1023
    const int bsub  = lane >> 4;
    const int jq    = lane & 15;
    const int b     = wvid * 4 + bsub;
    const int j0    = jq * 4;

    const float4* wt = wtab + (size_t)b * IN;
    const int*    kt = ktab + (size_t)b * IN;

    double acc[4] = {0.0, 0.0, 0.0, 0.0};

    // tables dist 2 (k per-lane, uniform within each 16-lane group)
    float4 wA = wt[0];
    int    kA = kt[0];
    float4 wB = wA; int kB = kA;
    if (IN > 1) { wB = wt[1]; kB = kt[1]; }

    f4a c0, c1, c2, c3;
    {
        const float* p = Ct + (size_t)kA * 64 + j0;   // i = 0
        c0 = *(const f4a*)(p);       c1 = *(const f4a*)(p + 64);
        c2 = *(const f4a*)(p + 128); c3 = *(const f4a*)(p + 192);
    }

    for (int i = 0; i < IN; ++i) {
        const int ip1 = (i + 1 < IN) ? i + 1 : IN - 1;
        const int ip2 = (i + 2 < IN) ? i + 2 : IN - 1;
        f4a n0, n1, n2, n3;
        {
            const float* p = Ct + ((size_t)ip1 * 64 + kB) * 64 + j0;
            n0 = *(const f4a*)(p);       n1 = *(const f4a*)(p + 64);
            n2 = *(const f4a*)(p + 128); n3 = *(const f4a*)(p + 192);
        }
        const float4 wC = wt[ip2];
        const int    kC = kt[ip2];
        const double w0 = (double)wA.x, w1 = (double)wA.y;
        const double w2 = (double)wA.z, w3 = (double)wA.w;
        #pragma unroll
        for (int e = 0; e < 4; ++e) {
            acc[e] = fma(w0, (double)c0[e], acc[e]);
            acc[e] = fma(w1, (double)c1[e], acc[e]);
            acc[e] = fma(w2, (double)c2[e], acc[e]);
            acc[e] = fma(w3, (double)c3[e], acc[e]);
        }
        wA = wB; kA = kB; wB = wC; kB = kC;
        c0 = n0; c1 = n1; c2 = n2; c3 = n3;
    }

    const float4 o = make_float4((float)acc[0], (float)acc[1],
                                 (float)acc[2], (float)acc[3]);
    *(float4*)(outp + (size_t)b * 64 + j0) = o;    // 1KB/wave coalesced
}

// ---------------- tier B: R9 proven path ([i][b] tables, row gather) --------

__global__ __launch_bounds__(256) void precomp_basis(const float* __restrict__ act,
        int IN, int transposed, float4* __restrict__ wtab, int* __restrict__ ktab,
        int total) {
    int gid = blockIdx.x * 256 + threadIdx.x;
    if (gid >= total) return;
    const int i = gid >> 12;
    const int b = gid & 4095;
    const float xf = transposed ? act[gid] : act[(size_t)b * IN + i];
    float4 wv; int kv;
    make_wk(xf, wv, kv);
    wtab[gid] = wv;
    ktab[gid] = kv;
}

template<int IN, int OUT, int JPT, bool TSTORE>
__global__ __launch_bounds__(256) void kan_direct(const float* __restrict__ Cg,
        const float4* __restrict__ wtab, const int* __restrict__ ktab,
        float* __restrict__ aout) {
    constexpr int JSPAN = 4 * JPT;
    constexpr int NJT = OUT / JSPAN;
    const int bid = blockIdx.x, tid = threadIdx.x;
    const int jt   = bid % NJT;
    const int bblk = bid / NJT;
    const int bl = tid & 63;
    const int jc = tid >> 6;
    const int j0 = jt * JSPAN + jc * JPT;
    const int b  = bblk * 64 + bl;

    double acc[JPT];
    #pragma unroll
    for (int m = 0; m < JPT; ++m) acc[m] = 0.0;

    float4 wv = wtab[b];
    int    kv = ktab[b];
    const float* Crow = Cg + (size_t)j0 * 64;

    for (int i = 0; i < IN; ++i) {
        const float4 wcur = wv;
        const int    kcur = kv;
        if (i + 1 < IN) {
            wv = wtab[(size_t)(i + 1) * 4096 + b];
            kv = ktab[(size_t)(i + 1) * 4096 + b];
        }
        const float* base = Crow + kcur;
        const double w0 = (double)wcur.x, w1 = (double)wcur.y;
        const double w2 = (double)wcur.z, w3 = (double)wcur.w;
        #pragma unroll
        for (int m = 0; m < JPT; ++m) {
            const f4a c = *(const f4a*)(base + m * 64);
            acc[m] = fma(w0, (double)c.x, acc[m]);
            acc[m] = fma(w1, (double)c.y, acc[m]);
            acc[m] = fma(w2, (double)c.z, acc[m]);
            acc[m] = fma(w3, (double)c.w, acc[m]);
        }
        Crow += (size_t)OUT * 64;
    }

    if (TSTORE) {
        #pragma unroll
        for (int m = 0; m < JPT; ++m)
            aout[(size_t)(j0 + m) * 4096 + b] = (float)acc[m];
    } else {
        #pragma unroll
        for (int m = 0; m < JPT; ++m)
            aout[(size_t)b * OUT + j0 + m] = (float)acc[m];
    }
}

// ---------------- tier C: R6 monolithic (zero workspace, proven) ------------

__device__ __forceinline__ void stage1(float xf, float sw[4], int& st) {
    const bool inr = (xf >= 0.0f) && (xf < 1.0f);
    if (!inr) { st = -1; sw[0] = sw[1] = sw[2] = sw[3] = 0.0f; return; }
    int t; float w[4];
    basis4(xf, t, w);
    sw[0] = w[0]; sw[1] = w[1]; sw[2] = w[2]; sw[3] = w[3];
    st = t;
}

template<int IN, int OUT>
__device__ __forceinline__ float gather_acc(const float* __restrict__ C, int j,
                                            const float (*__restrict__ sw)[4],
                                            const int* __restrict__ st) {
    double acc = 0.0;
    for (int i = 0; i < IN; ++i) {
        const int t = st[i];
        if (t < 0) continue;
        const float* Crow = C + ((size_t)i * OUT + j) * 64;
        #pragma unroll
        for (int r = 0; r < 4; ++r) {
            const int k4 = t - 3 + r;
            if (k4 >= 0 && k4 <= 63)
                acc += (double)sw[i][r] * (double)Crow[k4];
        }
    }
    return (float)acc;
}

__global__ __launch_bounds__(256) void kan_fused(const float* __restrict__ x,
                                                 const float* __restrict__ C0,
                                                 const float* __restrict__ C1,
                                                 const float* __restrict__ C2,
                                                 float* __restrict__ out) {
    __shared__ float cur[256];
    __shared__ float sw[256][4];
    __shared__ int   st[256];
    const int b = blockIdx.x, tid = threadIdx.x;

    if (tid < 64) stage1(x[(size_t)b * 64 + tid], sw[tid], st[tid]);
    __syncthreads();
    {
        const float a = gather_acc<64, 256>(C0, tid, sw, st);
        __syncthreads();
        cur[tid] = a;
    }
    __syncthreads();

    stage1(cur[tid], sw[tid], st[tid]);
    __syncthreads();
    {
        const float a = gather_acc<256, 256>(C1, tid, sw, st);
        __syncthreads();
        cur[tid] = a;
    }
    __syncthreads();

    stage1(cur[tid], sw[tid], st[tid]);
    __syncthreads();
    if (tid < 64) out[(size_t)b * 64 + tid] = gather_acc<256, 64>(C2, tid, sw, st);
}

// ---------------- launcher --------------------------------------------------

extern "C" void kernel_launch(void* const* d_in, const int* in_sizes, int n_in,
                              void* d_out, int out_size, void* d_ws, size_t ws_size,
                              hipStream_t stream) {
    const float* x  = (const float*)d_in[0];   // (4096, 64)
    const float* C0 = (const float*)d_in[1];   // (64, 256, 64)
    const float* C1 = (const float*)d_in[2];   // (256, 256, 64)
    const float* C2 = (const float*)d_in[3];   // (256, 64, 64)
    float* out = (float*)d_out;                // (4096, 64)

    const size_t WTAB = (size_t)4096 * 256 * 16;   // 16.78 MB
    const size_t KTAB = (size_t)4096 * 256 * 4;    //  4.19 MB
    const size_t CT1  = (size_t)256 * 64 * 256 * 4;// 16.78 MB (parks a1, then Ct1, then Ct2)
    const size_t ACT  = (size_t)4096 * 256 * 4;    //  4.19 MB (Ct0, then a2)
    const size_t needA = WTAB + KTAB + CT1 + ACT;  // 41.94 MB == R10-R12 proven
    const size_t needB = WTAB + KTAB + 2 * ACT;    // 29.36 MB (R9 proven)

    if (ws_size >= needA) {
        float4* wA   = (float4*)d_ws;
        int*    kA   = (int*)  ((char*)d_ws + WTAB);
        float*  ct1  = (float*)((char*)d_ws + WTAB + KTAB);
        float*  actb = (float*)((char*)d_ws + WTAB + KTAB + CT1);
        float*  a1   = ct1;   // parks in Ct1 slot, dead before C1 transpose
        float*  ct0  = actb;  // dead before a2 written
        float*  ct2  = ct1;   // overwrites dead Ct1 after layer 2
        float*  a2   = actb;  // overwrites dead Ct0 after layer 2

        transpose_nt<256><<<dim3(2, 8, 64), dim3(32, 8), 0, stream>>>(C0, ct0);
        precomp_bi<<<1024, 256, 0, stream>>>(x, wA, kA, 64 * 4096);
        kan_colgather<64, 256><<<1024, 256, 0, stream>>>(ct0, wA, kA, a1);
        precomp_bi<<<4096, 256, 0, stream>>>(a1, wA, kA, 256 * 4096);
        transpose_nt<256><<<dim3(2, 8, 256), dim3(32, 8), 0, stream>>>(C1, ct1);
        kan_colgather<256, 256><<<1024, 256, 0, stream>>>(ct1, wA, kA, a2);
        transpose_nt<64><<<dim3(2, 2, 256), dim3(32, 8), 0, stream>>>(C2, ct2);
        precomp_bi<<<4096, 256, 0, stream>>>(a2, wA, kA, 256 * 4096);
        kan_colgather4b<256><<<256, 256, 0, stream>>>(ct2, wA, kA, out);
    } else if (ws_size >= needB) {
        float4* wtab = (float4*)d_ws;
        int*    ktab = (int*)((char*)d_ws + WTAB);
        float*  a1T  = (float*)((char*)d_ws + WTAB + KTAB);
        float*  a2T  = a1T + (size_t)4096 * 256;

        precomp_basis<<<1024, 256, 0, stream>>>(x, 64, 0, wtab, ktab, 64 * 4096);
        kan_direct<64, 256, 4, true><<<1024, 256, 0, stream>>>(C0, wtab, ktab, a1T);
        precomp_basis<<<4096, 256, 0, stream>>>(a1T, 256, 1, wtab, ktab, 256 * 4096);
        kan_direct<256, 256, 4, true><<<1024, 256, 0, stream>>>(C1, wtab, ktab, a2T);
        precomp_basis<<<4096, 256, 0, stream>>>(a2T, 256, 1, wtab, ktab, 256 * 4096);
        kan_direct<256, 64, 1, false><<<1024, 256, 0, stream>>>(C2, wtab, ktab, out);
    } else {
        kan_fused<<<NBATCH, 256, 0, stream>>>(x, C0, C1, C2, out);
    }
}

// Round 14
// 370.726 us; speedup vs baseline: 1.6109x; 1.1008x over previous
//
#include <hip/hip_runtime.h>

// KAN forward: 3 layers of [deg-3 B-spline basis (64 bases) -> einsum 'bik,ijk->bj'].
// Only 4 basis values are nonzero per point => 4-tap gather per (i,j).
//
// NUMERICS (frozen since R6 — absmax sits exactly at threshold; per-(b,j)
// product set and fp64 add order must stay bitwise-identical):
//  * knots: jnp.linspace fp32 semantics, endpoint forced to 1.0f
//  * basis: fp32 Cox-de Boor, reference expression tree, contraction OFF
//  * einsum: fp64 accumulation, per-(b,j) order = i ascending, k ascending
//
// PERF: R6 1967 -> R7 711 -> R8 636 -> R9 420 -> R10 424 -> R11 404 -> R12
// 597 (small-request regression) -> R13 408.  Measured law: VMEM costs ~27
// cyc/CU per wave-load regardless of size => maximize bytes/load (1KB b128)
// and minimize load count.  Layer-2 main loop is AT its 4.2M-load floor
// (183us).  R14: layer 3 FUSED into layer-2 epilogue (its 4-row tap block is
// 1KB contiguous in Ct2[i][k][j] = ONE wave-load; 1.05M loads at 16 waves/CU
// vs 4 waves/CU before); per-kernel LDS prologue tables from raw activations
// (kills all precomp dispatches + 21MB table traffic).  5 dispatches, 25.2MB
// workspace, a1 is the only inter-kernel tensor.

#define NBATCH 4096

typedef float f4a __attribute__((ext_vector_type(4), aligned(4)));

// jnp.linspace(0,1,68,f32): delta = fl32(1/67); K[m] = fl32(m)*delta; K[67]=1.
__device__ __forceinline__ float knotf(int m) {
    if (m == 67) return 1.0f;
    return (float)m * (1.0f / 67.0f);
}

// Bitwise replica of the reference Cox-de Boor recursion on the 7-wide
// nonzero window around span t.  w[r] = B_{t-3+r,3}(x), r=0..3.
__device__ __forceinline__ void basis4(float xf, int& t_out, float w[4]) {
#pragma clang fp contract(off)
    int t = (int)floorf(xf * 67.0f);
    t = t < 0 ? 0 : (t > 66 ? 66 : t);
    #pragma unroll
    for (int it = 0; it < 2; ++it) {   // enforce K[t] <= x < K[t+1] on fp32 knots
        if (t > 0 && xf < knotf(t)) --t;
        else if (t < 66 && xf >= knotf(t + 1)) ++t;
    }
    float W[7];
    #pragma unroll
    for (int j = 0; j < 7; ++j) W[j] = 0.0f;
    W[3] = 1.0f;   // degree-0 indicator at span t
    #pragma unroll
    for (int d = 1; d <= 3; ++d) {
        #pragma unroll
        for (int j = 0; j <= 6 - d; ++j) {
            const int k = t - 3 + j;
            const float ka = knotf(k);
            const float kb = knotf(k + d);
            const float kc = knotf(k + d + 1);
            const float ke = knotf(k + 1);
            const float lt = ((xf - ka) / (kb - ka)) * W[j];
            const float rt = ((kc - xf) / (kc - ke)) * W[j + 1];
            W[j] = lt + rt;
        }
    }
    t_out = t;
    w[0] = W[0]; w[1] = W[1]; w[2] = W[2]; w[3] = W[3];
}

// Shift-aligned table entry: k0 = clamp(t-3,0,60); w'[m] applies to C[k0+m],
// m-ascending == k-ascending == R6 order; displaced/OOB slots get w'=0
// (+/-0-product adds are bitwise no-ops — validated R7-R13).
__device__ __forceinline__ void make_wk(float xf, float4& wv, int& kv) {
    float wp[4] = {0.f, 0.f, 0.f, 0.f};
    int k0 = 0;
    if (xf >= 0.0f && xf < 1.0f) {
        int t; float w[4];
        basis4(xf, t, w);
        k0 = t - 3;
        k0 = k0 < 0 ? 0 : (k0 > 60 ? 60 : k0);
        const int s = (t - 3) - k0;
        #pragma unroll
        for (int m = 0; m < 4; ++m) {
            const int r = m - s;
            wp[m] = (r >= 0 && r <= 3) ? w[r] : 0.0f;
        }
    }
    wv = make_float4(wp[0], wp[1], wp[2], wp[3]);
    kv = k0;
}

// ---------------- C transpose: C[i][j][k] -> Ct[i][k][j] --------------------
template<int OUT>
__global__ void transpose_nt(const float* __restrict__ C, float* __restrict__ Ct) {
    __shared__ float tile[32][33];
    const int i  = blockIdx.z;
    const int k0 = blockIdx.x * 32;
    const int j0 = blockIdx.y * 32;
    const float* src = C + (size_t)i * OUT * 64;
    #pragma unroll
    for (int r = threadIdx.y; r < 32; r += 8)
        tile[r][threadIdx.x] = src[(size_t)(j0 + r) * 64 + (k0 + threadIdx.x)];
    __syncthreads();
    float* dst = Ct + (size_t)i * 64 * OUT;
    #pragma unroll
    for (int r = threadIdx.y; r < 32; r += 8)
        dst[(size_t)(k0 + r) * OUT + (j0 + threadIdx.x)] = tile[threadIdx.x][r];
}

// ---------------- fused column-parallel layer kernel ------------------------
// Wave = one b; lane owns j-quad [4*lane..4*lane+3] of the 256-wide output.
// PROLOGUE: each lane computes make_wk from the raw activations for its
// entries and writes the (w,k) table to wave-private LDS (same-wave produce/
// consume: DS pipe is in-order per wave, compiler inserts lgkm waits — no
// barrier).  MAIN LOOP: per i, k is wave-uniform (readfirstlane -> SGPR
// addressing), 4x 1KB b128 row loads from Ct[i][k..k+3][:], 16 f64 FMA
// (i-asc, k-asc == R6 order), dist-1 prefetch.
// EPILOGUE: FUSE3=false -> store activations (a1).  FUSE3=true -> layer 3 in
// place: lane's 4 accs ARE a2[b][4l..4l+3]; make_wk -> LDS table (overwrites
// prologue table); loop i2: ONE 1KB load grabs the whole contiguous 4-row
// tap block of Ct2[i2][k..k+3][0..63] (lane l = tap r=l>>4, j-quad l&15),
// redistribute via a 1KB LDS bounce, 4 f64 FMA per j on 16 lanes.
template<int IN, bool FUSE3>
__global__ __launch_bounds__(256) void kan_col(
        const float* __restrict__ actin,   // [4096][IN] raw activations
        const float* __restrict__ Ct,      // [IN][64][256]
        const float* __restrict__ Ct2,     // [256][64][64] (FUSE3 only)
        float* __restrict__ outp) {        // !FUSE3: a1 [4096][256]; FUSE3: out [4096][64]
    __shared__ __align__(16) float4 wlds[4][256];
    __shared__ int                  klds[4][256];
    __shared__ __align__(16) f4a    cbuf[4][64];

    const int tid  = threadIdx.x;
    const int lane = tid & 63;
    const int wx   = tid >> 6;
    const int b    = blockIdx.x * 4 + wx;
    const int j0   = lane * 4;

    // ---- prologue: build (w,k) table for this b in LDS ----
    #pragma unroll
    for (int e = lane; e < IN; e += 64) {
        float4 wv; int kv;
        make_wk(actin[(size_t)b * IN + e], wv, kv);
        wlds[wx][e] = wv;
        klds[wx][e] = kv;
    }

    // ---- main gather loop (dist-1 prefetch) ----
    double acc[4] = {0.0, 0.0, 0.0, 0.0};
    float4 wA = wlds[wx][0];
    int    kA = __builtin_amdgcn_readfirstlane(klds[wx][0]);
    f4a cc0, cc1, cc2, cc3;
    {
        const float* p = Ct + (size_t)kA * 256 + j0;
        cc0 = *(const f4a*)(p);       cc1 = *(const f4a*)(p + 256);
        cc2 = *(const f4a*)(p + 512); cc3 = *(const f4a*)(p + 768);
    }
    for (int i = 0; i < IN; ++i) {
        const int ip1 = (i + 1 < IN) ? i + 1 : IN - 1;
        const float4 wN = wlds[wx][ip1];
        const int    kN = __builtin_amdgcn_readfirstlane(klds[wx][ip1]);
        f4a cn0, cn1, cn2, cn3;
        {
            const float* p = Ct + ((size_t)ip1 * 64 + kN) * 256 + j0;
            cn0 = *(const f4a*)(p);       cn1 = *(const f4a*)(p + 256);
            cn2 = *(const f4a*)(p + 512); cn3 = *(const f4a*)(p + 768);
        }
        const double w0 = (double)wA.x, w1 = (double)wA.y;
        const double w2 = (double)wA.z, w3 = (double)wA.w;
        #pragma unroll
        for (int e = 0; e < 4; ++e) {
            acc[e] = fma(w0, (double)cc0[e], acc[e]);   // k-ascending == R6
            acc[e] = fma(w1, (double)cc1[e], acc[e]);
            acc[e] = fma(w2, (double)cc2[e], acc[e]);
            acc[e] = fma(w3, (double)cc3[e], acc[e]);
        }
        wA = wN; kA = kN;
        cc0 = cn0; cc1 = cn1; cc2 = cn2; cc3 = cn3;
    }

    if (!FUSE3) {
        // activations out (a1[b][j0..j0+3]) — 1KB/wave coalesced
        const float4 o = make_float4((float)acc[0], (float)acc[1],
                                     (float)acc[2], (float)acc[3]);
        *(float4*)(outp + (size_t)b * 256 + j0) = o;
        return;
    }

    // ---- fused layer 3 ----
    // lane's accs are a2[b][4l..4l+3]; same fp32 rounding point as before.
    #pragma unroll
    for (int e = 0; e < 4; ++e) {
        float4 wv; int kv;
        make_wk((float)acc[e], wv, kv);
        wlds[wx][j0 + e] = wv;     // overwrite prologue table (same-wave order)
        klds[wx][j0 + e] = kv;
    }

    const int jq = lane & 15;
    double acc3[4] = {0.0, 0.0, 0.0, 0.0};

    int ks = __builtin_amdgcn_readfirstlane(klds[wx][0]);
    f4a vpend = *(const f4a*)(Ct2 + (size_t)ks * 64 + lane * 4);  // i2=0 block
    for (int i2 = 0; i2 < 256; ++i2) {
        const f4a vcur = vpend;
        const float4 wv = wlds[wx][i2];
        const int ip = (i2 + 1 < 256) ? i2 + 1 : 255;
        const int ksN = __builtin_amdgcn_readfirstlane(klds[wx][ip]);
        vpend = *(const f4a*)(Ct2 + ((size_t)ip * 64 + ksN) * 64 + lane * 4);
        // bounce current block through LDS: lane l wrote (r=l>>4, jq=l&15)
        cbuf[wx][lane] = vcur;
        const f4a c0 = cbuf[wx][jq];
        const f4a c1 = cbuf[wx][16 + jq];
        const f4a c2 = cbuf[wx][32 + jq];
        const f4a c3 = cbuf[wx][48 + jq];
        const double w0 = (double)wv.x, w1 = (double)wv.y;
        const double w2 = (double)wv.z, w3 = (double)wv.w;
        #pragma unroll
        for (int e = 0; e < 4; ++e) {
            acc3[e] = fma(w0, (double)c0[e], acc3[e]);   // k-ascending == R6
            acc3[e] = fma(w1, (double)c1[e], acc3[e]);
            acc3[e] = fma(w2, (double)c2[e], acc3[e]);
            acc3[e] = fma(w3, (double)c3[e], acc3[e]);
        }
    }

    if (lane < 16) {
        const float4 o = make_float4((float)acc3[0], (float)acc3[1],
                                     (float)acc3[2], (float)acc3[3]);
        *(float4*)(outp + (size_t)b * 64 + jq * 4) = o;
    }
}

// ---------------- fallback: R6 monolithic (zero workspace, proven) ----------

__device__ __forceinline__ void stage1(float xf, float sw[4], int& st) {
    const bool inr = (xf >= 0.0f) && (xf < 1.0f);
    if (!inr) { st = -1; sw[0] = sw[1] = sw[2] = sw[3] = 0.0f; return; }
    int t; float w[4];
    basis4(xf, t, w);
    sw[0] = w[0]; sw[1] = w[1]; sw[2] = w[2]; sw[3] = w[3];
    st = t;
}

template<int IN, int OUT>
__device__ __forceinline__ float gather_acc(const float* __restrict__ C, int j,
                                            const float (*__restrict__ sw)[4],
                                            const int* __restrict__ st) {
    double acc = 0.0;
    for (int i = 0; i < IN; ++i) {
        const int t = st[i];
        if (t < 0) continue;
        const float* Crow = C + ((size_t)i * OUT + j) * 64;
        #pragma unroll
        for (int r = 0; r < 4; ++r) {
            const int k4 = t - 3 + r;
            if (k4 >= 0 && k4 <= 63)
                acc += (double)sw[i][r] * (double)Crow[k4];
        }
    }
    return (float)acc;
}

__global__ __launch_bounds__(256) void kan_fused(const float* __restrict__ x,
                                                 const float* __restrict__ C0,
                                                 const float* __restrict__ C1,
                                                 const float* __restrict__ C2,
                                                 float* __restrict__ out) {
    __shared__ float cur[256];
    __shared__ float sw[256][4];
    __shared__ int   st[256];
    const int b = blockIdx.x, tid = threadIdx.x;

    if (tid < 64) stage1(x[(size_t)b * 64 + tid], sw[tid], st[tid]);
    __syncthreads();
    {
        const float a = gather_acc<64, 256>(C0, tid, sw, st);
        __syncthreads();
        cur[tid] = a;
    }
    __syncthreads();

    stage1(cur[tid], sw[tid], st[tid]);
    __syncthreads();
    {
        const float a = gather_acc<256, 256>(C1, tid, sw, st);
        __syncthreads();
        cur[tid] = a;
    }
    __syncthreads();

    stage1(cur[tid], sw[tid], st[tid]);
    __syncthreads();
    if (tid < 64) out[(size_t)b * 64 + tid] = gather_acc<256, 64>(C2, tid, sw, st);
}

// ---------------- launcher --------------------------------------------------

extern "C" void kernel_launch(void* const* d_in, const int* in_sizes, int n_in,
                              void* d_out, int out_size, void* d_ws, size_t ws_size,
                              hipStream_t stream) {
    const float* x  = (const float*)d_in[0];   // (4096, 64)
    const float* C0 = (const float*)d_in[1];   // (64, 256, 64)
    const float* C1 = (const float*)d_in[2];   // (256, 256, 64)
    const float* C2 = (const float*)d_in[3];   // (256, 64, 64)
    float* out = (float*)d_out;                // (4096, 64)

    const size_t CT1  = (size_t)256 * 64 * 256 * 4;  // 16.78 MB
    const size_t SLOT = (size_t)64 * 64 * 256 * 4;   //  4.19 MB (Ct0, later Ct2 — same size)
    const size_t A1   = (size_t)4096 * 256 * 4;      //  4.19 MB
    const size_t need = CT1 + SLOT + A1;             // 25.17 MB (< 41.94 proven)

    if (ws_size >= need) {
        float* ct1  = (float*)d_ws;
        float* slot = (float*)((char*)d_ws + CT1);
        float* a1   = (float*)((char*)d_ws + CT1 + SLOT);

        transpose_nt<256><<<dim3(2, 8, 64), dim3(32, 8), 0, stream>>>(C0, slot);
        kan_col<64, false><<<1024, 256, 0, stream>>>(x, slot, nullptr, a1);
        transpose_nt<64><<<dim3(2, 2, 256), dim3(32, 8), 0, stream>>>(C2, slot); // slot dead, reuse
        transpose_nt<256><<<dim3(2, 8, 256), dim3(32, 8), 0, stream>>>(C1, ct1);
        kan_col<256, true><<<1024, 256, 0, stream>>>(a1, ct1, slot, out);
    } else {
        kan_fused<<<NBATCH, 256, 0, stream>>>(x, C0, C1, C2, out);
    }
}

// Round 15
// 329.775 us; speedup vs baseline: 1.8110x; 1.1242x over previous
//
#include <hip/hip_runtime.h>

// KAN forward: 3 layers of [deg-3 B-spline basis (64 bases) -> einsum 'bik,ijk->bj'].
// Only 4 basis values are nonzero per point => 4-tap gather per (i,j).
//
// NUMERICS (frozen since R6 — absmax sits exactly at threshold; per-(b,j)
// product set and fp64 add order must stay bitwise-identical):
//  * knots: jnp.linspace fp32 semantics, endpoint forced to 1.0f
//  * basis: fp32 Cox-de Boor, reference expression tree, contraction OFF
//  * einsum: fp64 accumulation, per-(b,j) order = i ascending, k ascending
//    (shift-aligned w' slots: +/-0-product adds are bitwise no-ops, R7-R14)
//
// PERF: R6 1967 -> R7 711 -> R8 636 -> R9 420 -> R11 404 -> R13 408 -> R14
// 371.  Measured law: VMEM costs ~27 cyc/CU per wave-load REGARDLESS of size
// => the L2 main loop's 4.2M-load floor is 183us (hard; bytes irreducible,
// no cross-block reuse possible).  R14's L3 phase was 105us: 4x-redundant
// f64 FMA (64 lanes compute, 16 store).  R15: single mega-kernel (wave = one
// b through L1+L2, no a1 round-trip); after ONE barrier, wave 0 runs L3 for
// all 4 b's with lane=(bsub,jq) — 4-segment 1KB loads (per-bsub k0 in the
// address, no LDS bounce), FMA at the 27us useful floor, dist-2 prefetch.

#define NBATCH 4096

typedef float f4a __attribute__((ext_vector_type(4), aligned(4)));

// jnp.linspace(0,1,68,f32): delta = fl32(1/67); K[m] = fl32(m)*delta; K[67]=1.
__device__ __forceinline__ float knotf(int m) {
    if (m == 67) return 1.0f;
    return (float)m * (1.0f / 67.0f);
}

// Bitwise replica of the reference Cox-de Boor recursion on the 7-wide
// nonzero window around span t.  w[r] = B_{t-3+r,3}(x), r=0..3.
__device__ __forceinline__ void basis4(float xf, int& t_out, float w[4]) {
#pragma clang fp contract(off)
    int t = (int)floorf(xf * 67.0f);
    t = t < 0 ? 0 : (t > 66 ? 66 : t);
    #pragma unroll
    for (int it = 0; it < 2; ++it) {   // enforce K[t] <= x < K[t+1] on fp32 knots
        if (t > 0 && xf < knotf(t)) --t;
        else if (t < 66 && xf >= knotf(t + 1)) ++t;
    }
    float W[7];
    #pragma unroll
    for (int j = 0; j < 7; ++j) W[j] = 0.0f;
    W[3] = 1.0f;   // degree-0 indicator at span t
    #pragma unroll
    for (int d = 1; d <= 3; ++d) {
        #pragma unroll
        for (int j = 0; j <= 6 - d; ++j) {
            const int k = t - 3 + j;
            const float ka = knotf(k);
            const float kb = knotf(k + d);
            const float kc = knotf(k + d + 1);
            const float ke = knotf(k + 1);
            const float lt = ((xf - ka) / (kb - ka)) * W[j];
            const float rt = ((kc - xf) / (kc - ke)) * W[j + 1];
            W[j] = lt + rt;
        }
    }
    t_out = t;
    w[0] = W[0]; w[1] = W[1]; w[2] = W[2]; w[3] = W[3];
}

// Shift-aligned table entry: k0 = clamp(t-3,0,60); w'[m] applies to C[k0+m],
// m-ascending == k-ascending == R6 order; displaced/OOB slots get w'=0
// (+/-0-product adds are bitwise no-ops — validated R7-R14).
__device__ __forceinline__ void make_wk(float xf, float4& wv, int& kv) {
    float wp[4] = {0.f, 0.f, 0.f, 0.f};
    int k0 = 0;
    if (xf >= 0.0f && xf < 1.0f) {
        int t; float w[4];
        basis4(xf, t, w);
        k0 = t - 3;
        k0 = k0 < 0 ? 0 : (k0 > 60 ? 60 : k0);
        const int s = (t - 3) - k0;
        #pragma unroll
        for (int m = 0; m < 4; ++m) {
            const int r = m - s;
            wp[m] = (r >= 0 && r <= 3) ? w[r] : 0.0f;
        }
    }
    wv = make_float4(wp[0], wp[1], wp[2], wp[3]);
    kv = k0;
}

// ---------------- C transpose: C[i][j][k] -> Ct[i][k][j] --------------------
template<int OUT>
__global__ void transpose_nt(const float* __restrict__ C, float* __restrict__ Ct) {
    __shared__ float tile[32][33];
    const int i  = blockIdx.z;
    const int k0 = blockIdx.x * 32;
    const int j0 = blockIdx.y * 32;
    const float* src = C + (size_t)i * OUT * 64;
    #pragma unroll
    for (int r = threadIdx.y; r < 32; r += 8)
        tile[r][threadIdx.x] = src[(size_t)(j0 + r) * 64 + (k0 + threadIdx.x)];
    __syncthreads();
    float* dst = Ct + (size_t)i * 64 * OUT;
    #pragma unroll
    for (int r = threadIdx.y; r < 32; r += 8)
        dst[(size_t)(k0 + r) * OUT + (j0 + threadIdx.x)] = tile[threadIdx.x][r];
}

// ---------------- main gather loop (OUT=256), proven 183us structure --------
// Wave = one b; lane owns j-quad; per i: wave-uniform k (readfirstlane ->
// SGPR addressing), 4x 1KB b128 row loads, 16 f64 FMA (i-asc, k-asc == R6),
// dist-1 prefetch.  wl/kl are this wave's LDS table (broadcast reads).
template<int IN>
__device__ __forceinline__ void gather_main(const float* __restrict__ Ct,
        const float4* __restrict__ wl, const int* __restrict__ kl,
        int j0, double acc[4]) {
    float4 wA = wl[0];
    int    kA = __builtin_amdgcn_readfirstlane(kl[0]);
    f4a cc0, cc1, cc2, cc3;
    {
        const float* p = Ct + (size_t)kA * 256 + j0;
        cc0 = *(const f4a*)(p);       cc1 = *(const f4a*)(p + 256);
        cc2 = *(const f4a*)(p + 512); cc3 = *(const f4a*)(p + 768);
    }
    for (int i = 0; i < IN; ++i) {
        const int ip1 = (i + 1 < IN) ? i + 1 : IN - 1;
        const float4 wN = wl[ip1];
        const int    kN = __builtin_amdgcn_readfirstlane(kl[ip1]);
        f4a cn0, cn1, cn2, cn3;
        {
            const float* p = Ct + ((size_t)ip1 * 64 + kN) * 256 + j0;
            cn0 = *(const f4a*)(p);       cn1 = *(const f4a*)(p + 256);
            cn2 = *(const f4a*)(p + 512); cn3 = *(const f4a*)(p + 768);
        }
        const double w0 = (double)wA.x, w1 = (double)wA.y;
        const double w2 = (double)wA.z, w3 = (double)wA.w;
        #pragma unroll
        for (int e = 0; e < 4; ++e) {
            acc[e] = fma(w0, (double)cc0[e], acc[e]);   // k-ascending == R6
            acc[e] = fma(w1, (double)cc1[e], acc[e]);
            acc[e] = fma(w2, (double)cc2[e], acc[e]);
            acc[e] = fma(w3, (double)cc3[e], acc[e]);
        }
        wA = wN; kA = kN;
        cc0 = cn0; cc1 = cn1; cc2 = cn2; cc3 = cn3;
    }
}

// ---------------- mega kernel: all 3 layers ---------------------------------
__global__ __launch_bounds__(256) void kan_mega(
        const float* __restrict__ x,       // [4096][64]
        const float* __restrict__ Ct0,     // [64][64][256]
        const float* __restrict__ Ct1,     // [256][64][256]
        const float* __restrict__ Ct2,     // [256][64][64]
        float* __restrict__ out) {         // [4096][64]
    __shared__ __align__(16) float4 wlds[4][256];
    __shared__ int                  klds[4][256];

    const int tid  = threadIdx.x;
    const int lane = tid & 63;
    const int wx   = tid >> 6;
    const int b    = blockIdx.x * 4 + wx;
    const int j0   = lane * 4;

    // ---- x-table (64 entries, one per lane) ----
    {
        float4 wv; int kv;
        make_wk(x[(size_t)b * 64 + lane], wv, kv);
        wlds[wx][lane] = wv;
        klds[wx][lane] = kv;
    }

    // ---- layer 1 ----
    double acc1[4] = {0.0, 0.0, 0.0, 0.0};
    gather_main<64>(Ct0, &wlds[wx][0], &klds[wx][0], j0, acc1);
    // a1 rounding + next table (same-wave DS order: write-after-read safe)
    #pragma unroll
    for (int e = 0; e < 4; ++e) {
        float4 wv; int kv;
        make_wk((float)acc1[e], wv, kv);   // same fp32 value R14 stored to a1
        wlds[wx][j0 + e] = wv;
        klds[wx][j0 + e] = kv;
    }

    // ---- layer 2 ----
    double acc2[4] = {0.0, 0.0, 0.0, 0.0};
    gather_main<256>(Ct1, &wlds[wx][0], &klds[wx][0], j0, acc2);
    // a2 rounding + layer-3 table (read cross-wave after barrier)
    #pragma unroll
    for (int e = 0; e < 4; ++e) {
        float4 wv; int kv;
        make_wk((float)acc2[e], wv, kv);
        wlds[wx][j0 + e] = wv;
        klds[wx][j0 + e] = kv;
    }
    __syncthreads();
    if (wx != 0) return;

    // ---- layer 3: wave 0 handles the block's 4 b's, lane = (bsub, jq) ----
    // Load r: lane reads Ct2[i2][k0(bsub)+r][jq*4..+3] -> 4 x 256B segments
    // per instr (1KB).  No LDS bounce; taps land in the owning lane.  fp64
    // chain per (b,j): i2 ascending, r (=k) ascending — bitwise == R14.
    const int bsub = lane >> 4;
    const int jq   = lane & 15;
    double a3[4] = {0.0, 0.0, 0.0, 0.0};

    // dist-2 pipeline: blocks for i2, i2+1 in flight
    f4a p0[4], p1[4];
    {
        const int k0 = klds[bsub][0];
        #pragma unroll
        for (int r = 0; r < 4; ++r)
            p0[r] = *(const f4a*)(Ct2 + (size_t)(k0 + r) * 64 + jq * 4);
    }
    {
        const int k1 = klds[bsub][1];
        #pragma unroll
        for (int r = 0; r < 4; ++r)
            p1[r] = *(const f4a*)(Ct2 + 4096 + (size_t)(k1 + r) * 64 + jq * 4);
    }

    for (int i2 = 0; i2 < 256; ++i2) {
        const int ip2 = (i2 + 2 < 256) ? i2 + 2 : 255;
        const int kP  = klds[bsub][ip2];
        f4a p2[4];
        #pragma unroll
        for (int r = 0; r < 4; ++r)
            p2[r] = *(const f4a*)(Ct2 + (size_t)ip2 * 4096 + (size_t)(kP + r) * 64 + jq * 4);
        const float4 wv = wlds[bsub][i2];
        const double w0 = (double)wv.x, w1 = (double)wv.y;
        const double w2 = (double)wv.z, w3 = (double)wv.w;
        #pragma unroll
        for (int e = 0; e < 4; ++e) {
            a3[e] = fma(w0, (double)p0[0][e], a3[e]);   // k-ascending == R6
            a3[e] = fma(w1, (double)p0[1][e], a3[e]);
            a3[e] = fma(w2, (double)p0[2][e], a3[e]);
            a3[e] = fma(w3, (double)p0[3][e], a3[e]);
        }
        #pragma unroll
        for (int r = 0; r < 4; ++r) { p0[r] = p1[r]; p1[r] = p2[r]; }
    }

    const float4 o = make_float4((float)a3[0], (float)a3[1],
                                 (float)a3[2], (float)a3[3]);
    *(float4*)(out + (size_t)(blockIdx.x * 4 + bsub) * 64 + jq * 4) = o;
}

// ---------------- fallback: R6 monolithic (zero workspace, proven) ----------

__device__ __forceinline__ void stage1(float xf, float sw[4], int& st) {
    const bool inr = (xf >= 0.0f) && (xf < 1.0f);
    if (!inr) { st = -1; sw[0] = sw[1] = sw[2] = sw[3] = 0.0f; return; }
    int t; float w[4];
    basis4(xf, t, w);
    sw[0] = w[0]; sw[1] = w[1]; sw[2] = w[2]; sw[3] = w[3];
    st = t;
}

template<int IN, int OUT>
__device__ __forceinline__ float gather_acc(const float* __restrict__ C, int j,
                                            const float (*__restrict__ sw)[4],
                                            const int* __restrict__ st) {
    double acc = 0.0;
    for (int i = 0; i < IN; ++i) {
        const int t = st[i];
        if (t < 0) continue;
        const float* Crow = C + ((size_t)i * OUT + j) * 64;
        #pragma unroll
        for (int r = 0; r < 4; ++r) {
            const int k4 = t - 3 + r;
            if (k4 >= 0 && k4 <= 63)
                acc += (double)sw[i][r] * (double)Crow[k4];
        }
    }
    return (float)acc;
}

__global__ __launch_bounds__(256) void kan_fused(const float* __restrict__ x,
                                                 const float* __restrict__ C0,
                                                 const float* __restrict__ C1,
                                                 const float* __restrict__ C2,
                                                 float* __restrict__ out) {
    __shared__ float cur[256];
    __shared__ float sw[256][4];
    __shared__ int   st[256];
    const int b = blockIdx.x, tid = threadIdx.x;

    if (tid < 64) stage1(x[(size_t)b * 64 + tid], sw[tid], st[tid]);
    __syncthreads();
    {
        const float a = gather_acc<64, 256>(C0, tid, sw, st);
        __syncthreads();
        cur[tid] = a;
    }
    __syncthreads();

    stage1(cur[tid], sw[tid], st[tid]);
    __syncthreads();
    {
        const float a = gather_acc<256, 256>(C1, tid, sw, st);
        __syncthreads();
        cur[tid] = a;
    }
    __syncthreads();

    stage1(cur[tid], sw[tid], st[tid]);
    __syncthreads();
    if (tid < 64) out[(size_t)b * 64 + tid] = gather_acc<256, 64>(C2, tid, sw, st);
}

// ---------------- launcher --------------------------------------------------

extern "C" void kernel_launch(void* const* d_in, const int* in_sizes, int n_in,
                              void* d_out, int out_size, void* d_ws, size_t ws_size,
                              hipStream_t stream) {
    const float* x  = (const float*)d_in[0];   // (4096, 64)
    const float* C0 = (const float*)d_in[1];   // (64, 256, 64)
    const float* C1 = (const float*)d_in[2];   // (256, 256, 64)
    const float* C2 = (const float*)d_in[3];   // (256, 64, 64)
    float* out = (float*)d_out;                // (4096, 64)

    const size_t CT1 = (size_t)256 * 64 * 256 * 4;   // 16.78 MB
    const size_t CT0 = (size_t)64  * 64 * 256 * 4;   //  4.19 MB
    const size_t CT2 = (size_t)256 * 64 * 64  * 4;   //  4.19 MB
    const size_t need = CT1 + CT0 + CT2;             // 25.17 MB (== R14 proven)

    if (ws_size >= need) {
        float* ct1 = (float*)d_ws;
        float* ct0 = (float*)((char*)d_ws + CT1);
        float* ct2 = (float*)((char*)d_ws + CT1 + CT0);

        transpose_nt<256><<<dim3(2, 8, 64),  dim3(32, 8), 0, stream>>>(C0, ct0);
        transpose_nt<256><<<dim3(2, 8, 256), dim3(32, 8), 0, stream>>>(C1, ct1);
        transpose_nt<64> <<<dim3(2, 2, 256), dim3(32, 8), 0, stream>>>(C2, ct2);
        kan_mega<<<1024, 256, 0, stream>>>(x, ct0, ct1, ct2, out);
    } else {
        kan_fused<<<NBATCH, 256, 0, stream>>>(x, C0, C1, C2, out);
    }
}

// Round 16
// 213.082 us; speedup vs baseline: 2.8027x; 1.5476x over previous
//
#include <hip/hip_runtime.h>

// KAN forward: 3 layers of [deg-3 B-spline basis (64 bases) -> einsum 'bik,ijk->bj'].
// Only 4 basis values are nonzero per point => 4-tap gather per (i,j).
//
// NUMERICS (frozen since R6 — absmax sits exactly at threshold; per-(b,j)
// product set and fp64 add order must stay bitwise-identical):
//  * knots: jnp.linspace fp32 semantics, endpoint forced to 1.0f
//  * basis: fp32 Cox-de Boor, reference expression tree, contraction OFF
//  * einsum: fp64 accumulation, per-(b,j) order = i ascending, k ascending
//  * skipping an i whose 4 weights are all +/-0 only removes exact +/-0.0
//    adds — IEEE-exact no-ops incl. signed-zero cases (validated R7-R15)
//
// PERF: R6 1967 -> R7 711 -> R9 420 -> R11 404 -> R14 371 -> R15 330.
// R15 budget: L1 46 (request floor) + L2 183 (request floor) + L3 40.
// KEY STAT: a1 ~ N(0, 5.5^2) => only ~7% of layer-2 inputs land in [0,1)
// (nonzero basis); a2 ~ N(0, 2.9^2) => ~13% for layer 3.  R16: per-wave
// ballot-compacted active lists (i-order preserved) — L2/L3 loads and FMAs
// drop ~10x; L1 (all-active, x uniform[0,1)) unchanged and becomes dominant.

#define NBATCH 4096

typedef float f4a __attribute__((ext_vector_type(4), aligned(4)));

// jnp.linspace(0,1,68,f32): delta = fl32(1/67); K[m] = fl32(m)*delta; K[67]=1.
__device__ __forceinline__ float knotf(int m) {
    if (m == 67) return 1.0f;
    return (float)m * (1.0f / 67.0f);
}

// Bitwise replica of the reference Cox-de Boor recursion on the 7-wide
// nonzero window around span t.  w[r] = B_{t-3+r,3}(x), r=0..3.
__device__ __forceinline__ void basis4(float xf, int& t_out, float w[4]) {
#pragma clang fp contract(off)
    int t = (int)floorf(xf * 67.0f);
    t = t < 0 ? 0 : (t > 66 ? 66 : t);
    #pragma unroll
    for (int it = 0; it < 2; ++it) {   // enforce K[t] <= x < K[t+1] on fp32 knots
        if (t > 0 && xf < knotf(t)) --t;
        else if (t < 66 && xf >= knotf(t + 1)) ++t;
    }
    float W[7];
    #pragma unroll
    for (int j = 0; j < 7; ++j) W[j] = 0.0f;
    W[3] = 1.0f;   // degree-0 indicator at span t
    #pragma unroll
    for (int d = 1; d <= 3; ++d) {
        #pragma unroll
        for (int j = 0; j <= 6 - d; ++j) {
            const int k = t - 3 + j;
            const float ka = knotf(k);
            const float kb = knotf(k + d);
            const float kc = knotf(k + d + 1);
            const float ke = knotf(k + 1);
            const float lt = ((xf - ka) / (kb - ka)) * W[j];
            const float rt = ((kc - xf) / (kc - ke)) * W[j + 1];
            W[j] = lt + rt;
        }
    }
    t_out = t;
    w[0] = W[0]; w[1] = W[1]; w[2] = W[2]; w[3] = W[3];
}

// Shift-aligned table entry: k0 = clamp(t-3,0,60); w'[m] applies to C[k0+m],
// m-ascending == k-ascending == R6 order; displaced/OOB slots get w'=0.
__device__ __forceinline__ void make_wk(float xf, float4& wv, int& kv) {
    float wp[4] = {0.f, 0.f, 0.f, 0.f};
    int k0 = 0;
    if (xf >= 0.0f && xf < 1.0f) {
        int t; float w[4];
        basis4(xf, t, w);
        k0 = t - 3;
        k0 = k0 < 0 ? 0 : (k0 > 60 ? 60 : k0);
        const int s = (t - 3) - k0;
        #pragma unroll
        for (int m = 0; m < 4; ++m) {
            const int r = m - s;
            wp[m] = (r >= 0 && r <= 3) ? w[r] : 0.0f;
        }
    }
    wv = make_float4(wp[0], wp[1], wp[2], wp[3]);
    kv = k0;
}

// ---------------- C transpose: C[i][j][k] -> Ct[i][k][j] --------------------
template<int OUT>
__global__ void transpose_nt(const float* __restrict__ C, float* __restrict__ Ct) {
    __shared__ float tile[32][33];
    const int i  = blockIdx.z;
    const int k0 = blockIdx.x * 32;
    const int j0 = blockIdx.y * 32;
    const float* src = C + (size_t)i * OUT * 64;
    #pragma unroll
    for (int r = threadIdx.y; r < 32; r += 8)
        tile[r][threadIdx.x] = src[(size_t)(j0 + r) * 64 + (k0 + threadIdx.x)];
    __syncthreads();
    float* dst = Ct + (size_t)i * 64 * OUT;
    #pragma unroll
    for (int r = threadIdx.y; r < 32; r += 8)
        dst[(size_t)(k0 + r) * OUT + (j0 + threadIdx.x)] = tile[threadIdx.x][r];
}

// ---------------- wave compaction: raw (w,k) -> active (w, row-offset) ------
// Entry order e ascending (= i ascending) preserved.  Activity test treats
// -0.0 as zero ((-0.0f != 0.0f) is false) — such entries' products are +/-0,
// exact no-op adds.  Returns active count.
__device__ __forceinline__ int compact_wave(int lane, int passes,
        const float4* __restrict__ wsrc, const int* __restrict__ ksrc,
        float4* __restrict__ wdst, int* __restrict__ rdst, int mult) {
    int base = 0;
    for (int p = 0; p < passes; ++p) {
        const int e = 64 * p + lane;
        const float4 wv = wsrc[e];
        const int    kv = ksrc[e];
        const bool act = (wv.x != 0.f) || (wv.y != 0.f) ||
                         (wv.z != 0.f) || (wv.w != 0.f);
        const unsigned long long mask = __ballot(act);
        const int pos = base + (int)__popcll(mask & ((1ull << lane) - 1ull));
        if (act) { wdst[pos] = wv; rdst[pos] = (e * 64 + kv) * mult; }
        base += (int)__popcll(mask);
    }
    return base;   // wave-uniform
}

// ---------------- gather over an active list (OUT=256 layers) ---------------
// Wave = one b; lane owns j-quad.  Per entry: wave-uniform row offset
// (readfirstlane -> SGPR addressing), 4x 1KB b128 row loads, 16 f64 FMA
// (entry-asc = i-asc, k-asc == R6 order), dist-1 prefetch.
__device__ __forceinline__ void gather_list(const float* __restrict__ Ct,
        const float4* __restrict__ wl, const int* __restrict__ rl,
        int cnt, int j0, double acc[4]) {
    if (cnt <= 0) return;
    float4 wA = wl[0];
    int    rA = __builtin_amdgcn_readfirstlane(rl[0]);
    f4a cc0, cc1, cc2, cc3;
    {
        const float* p = Ct + rA + j0;
        cc0 = *(const f4a*)(p);       cc1 = *(const f4a*)(p + 256);
        cc2 = *(const f4a*)(p + 512); cc3 = *(const f4a*)(p + 768);
    }
    for (int e = 0; e < cnt; ++e) {
        const int ep = (e + 1 < cnt) ? e + 1 : cnt - 1;
        const float4 wN = wl[ep];
        const int    rN = __builtin_amdgcn_readfirstlane(rl[ep]);
        f4a cn0, cn1, cn2, cn3;
        {
            const float* p = Ct + rN + j0;
            cn0 = *(const f4a*)(p);       cn1 = *(const f4a*)(p + 256);
            cn2 = *(const f4a*)(p + 512); cn3 = *(const f4a*)(p + 768);
        }
        const double w0 = (double)wA.x, w1 = (double)wA.y;
        const double w2 = (double)wA.z, w3 = (double)wA.w;
        #pragma unroll
        for (int ee = 0; ee < 4; ++ee) {
            acc[ee] = fma(w0, (double)cc0[ee], acc[ee]);   // k-ascending == R6
            acc[ee] = fma(w1, (double)cc1[ee], acc[ee]);
            acc[ee] = fma(w2, (double)cc2[ee], acc[ee]);
            acc[ee] = fma(w3, (double)cc3[ee], acc[ee]);
        }
        wA = wN;
        cc0 = cn0; cc1 = cn1; cc2 = cn2; cc3 = cn3;
    }
}

// ---------------- mega kernel: all 3 layers, compacted L2/L3 ----------------
__global__ __launch_bounds__(256) void kan_mega2(
        const float* __restrict__ x,       // [4096][64]
        const float* __restrict__ Ct0,     // [64][64][256]
        const float* __restrict__ Ct1,     // [256][64][256]
        const float* __restrict__ Ct2,     // [256][64][64]
        float* __restrict__ out) {         // [4096][64]
    __shared__ __align__(16) float4 wraw[4][256];
    __shared__ int                  kraw[4][256];
    __shared__ __align__(16) float4 wcmp[4][256];
    __shared__ int                  rcmp[4][256];
    __shared__ int scnt[4];

    const int tid  = threadIdx.x;
    const int lane = tid & 63;
    const int wx   = tid >> 6;
    const int b    = blockIdx.x * 4 + wx;
    const int j0   = lane * 4;

    // ---- L1 table from x: 64 entries, all kept (x uniform in [0,1)) ----
    {
        float4 wv; int kv;
        make_wk(x[(size_t)b * 64 + lane], wv, kv);
        wraw[wx][lane] = wv;
        kraw[wx][lane] = (lane * 64 + kv) * 256;   // row offset directly
    }
    double acc1[4] = {0.0, 0.0, 0.0, 0.0};
    gather_list(Ct0, &wraw[wx][0], &kraw[wx][0], 64, j0, acc1);

    // ---- a1 rounding -> raw table -> compacted L2 list ----
    #pragma unroll
    for (int e = 0; e < 4; ++e) {
        float4 wv; int kv;
        make_wk((float)acc1[e], wv, kv);   // same fp32 value as R15
        wraw[wx][j0 + e] = wv;
        kraw[wx][j0 + e] = kv;
    }
    const int cnt2 = compact_wave(lane, 4, &wraw[wx][0], &kraw[wx][0],
                                  &wcmp[wx][0], &rcmp[wx][0], 256);

    double acc2[4] = {0.0, 0.0, 0.0, 0.0};
    gather_list(Ct1, &wcmp[wx][0], &rcmp[wx][0], cnt2, j0, acc2);

    // ---- a2 rounding -> raw table -> compacted L3 list ----
    #pragma unroll
    for (int e = 0; e < 4; ++e) {
        float4 wv; int kv;
        make_wk((float)acc2[e], wv, kv);
        wraw[wx][j0 + e] = wv;
        kraw[wx][j0 + e] = kv;
    }
    const int cnt3 = compact_wave(lane, 4, &wraw[wx][0], &kraw[wx][0],
                                  &wcmp[wx][0], &rcmp[wx][0], 64);
    if (lane == 0) scnt[wx] = cnt3;
    __syncthreads();
    if (wx != 0) return;

    // ---- layer 3 on wave 0: lane = (bsub, jq); 4-segment 1KB loads ----
    const int bsub = lane >> 4;
    const int jq   = lane & 15;
    const int cn   = scnt[bsub];
    const int cmax = max(max(scnt[0], scnt[1]), max(scnt[2], scnt[3]));
    double a3[4] = {0.0, 0.0, 0.0, 0.0};

    if (cmax > 0) {
        auto ldb = [&](int e, f4a p[4], float4& wv) {
            const int ec = (cn > 0) ? ((e < cn) ? e : cn - 1) : 0;
            wv = (cn > 0) ? wcmp[bsub][ec] : make_float4(0.f, 0.f, 0.f, 0.f);
            int ro = (cn > 0) ? rcmp[bsub][ec] : 0;
            if (e >= cn) wv = make_float4(0.f, 0.f, 0.f, 0.f);  // pad: exact no-op
            const float* pb = Ct2 + ro + jq * 4;
            p[0] = *(const f4a*)(pb);
            p[1] = *(const f4a*)(pb + 64);
            p[2] = *(const f4a*)(pb + 128);
            p[3] = *(const f4a*)(pb + 192);
        };
        f4a P0[4], P1[4]; float4 W0, W1;
        ldb(0, P0, W0);
        ldb(1, P1, W1);
        for (int e = 0; e < cmax; ++e) {
            f4a P2[4]; float4 W2;
            ldb(e + 2, P2, W2);
            const double w0 = (double)W0.x, w1 = (double)W0.y;
            const double w2 = (double)W0.z, w3 = (double)W0.w;
            #pragma unroll
            for (int ee = 0; ee < 4; ++ee) {
                a3[ee] = fma(w0, (double)P0[0][ee], a3[ee]);   // k-asc == R6
                a3[ee] = fma(w1, (double)P0[1][ee], a3[ee]);
                a3[ee] = fma(w2, (double)P0[2][ee], a3[ee]);
                a3[ee] = fma(w3, (double)P0[3][ee], a3[ee]);
            }
            #pragma unroll
            for (int r = 0; r < 4; ++r) { P0[r] = P1[r]; P1[r] = P2[r]; }
            W0 = W1; W1 = W2;
        }
    }

    const float4 o = make_float4((float)a3[0], (float)a3[1],
                                 (float)a3[2], (float)a3[3]);
    *(float4*)(out + (size_t)(blockIdx.x * 4 + bsub) * 64 + jq * 4) = o;
}

// ---------------- fallback: R6 monolithic (zero workspace, proven) ----------

__device__ __forceinline__ void stage1(float xf, float sw[4], int& st) {
    const bool inr = (xf >= 0.0f) && (xf < 1.0f);
    if (!inr) { st = -1; sw[0] = sw[1] = sw[2] = sw[3] = 0.0f; return; }
    int t; float w[4];
    basis4(xf, t, w);
    sw[0] = w[0]; sw[1] = w[1]; sw[2] = w[2]; sw[3] = w[3];
    st = t;
}

template<int IN, int OUT>
__device__ __forceinline__ float gather_acc(const float* __restrict__ C, int j,
                                            const float (*__restrict__ sw)[4],
                                            const int* __restrict__ st) {
    double acc = 0.0;
    for (int i = 0; i < IN; ++i) {
        const int t = st[i];
        if (t < 0) continue;
        const float* Crow = C + ((size_t)i * OUT + j) * 64;
        #pragma unroll
        for (int r = 0; r < 4; ++r) {
            const int k4 = t - 3 + r;
            if (k4 >= 0 && k4 <= 63)
                acc += (double)sw[i][r] * (double)Crow[k4];
        }
    }
    return (float)acc;
}

__global__ __launch_bounds__(256) void kan_fused(const float* __restrict__ x,
                                                 const float* __restrict__ C0,
                                                 const float* __restrict__ C1,
                                                 const float* __restrict__ C2,
                                                 float* __restrict__ out) {
    __shared__ float cur[256];
    __shared__ float sw[256][4];
    __shared__ int   st[256];
    const int b = blockIdx.x, tid = threadIdx.x;

    if (tid < 64) stage1(x[(size_t)b * 64 + tid], sw[tid], st[tid]);
    __syncthreads();
    {
        const float a = gather_acc<64, 256>(C0, tid, sw, st);
        __syncthreads();
        cur[tid] = a;
    }
    __syncthreads();

    stage1(cur[tid], sw[tid], st[tid]);
    __syncthreads();
    {
        const float a = gather_acc<256, 256>(C1, tid, sw, st);
        __syncthreads();
        cur[tid] = a;
    }
    __syncthreads();

    stage1(cur[tid], sw[tid], st[tid]);
    __syncthreads();
    if (tid < 64) out[(size_t)b * 64 + tid] = gather_acc<256, 64>(C2, tid, sw, st);
}

// ---------------- launcher --------------------------------------------------

extern "C" void kernel_launch(void* const* d_in, const int* in_sizes, int n_in,
                              void* d_out, int out_size, void* d_ws, size_t ws_size,
                              hipStream_t stream) {
    const float* x  = (const float*)d_in[0];   // (4096, 64)
    const float* C0 = (const float*)d_in[1];   // (64, 256, 64)
    const float* C1 = (const float*)d_in[2];   // (256, 256, 64)
    const float* C2 = (const float*)d_in[3];   // (256, 64, 64)
    float* out = (float*)d_out;                // (4096, 64)

    const size_t CT1 = (size_t)256 * 64 * 256 * 4;   // 16.78 MB
    const size_t CT0 = (size_t)64  * 64 * 256 * 4;   //  4.19 MB
    const size_t CT2 = (size_t)256 * 64 * 64  * 4;   //  4.19 MB
    const size_t need = CT1 + CT0 + CT2;             // 25.17 MB (R14/R15 proven)

    if (ws_size >= need) {
        float* ct1 = (float*)d_ws;
        float* ct0 = (float*)((char*)d_ws + CT1);
        float* ct2 = (float*)((char*)d_ws + CT1 + CT0);

        transpose_nt<256><<<dim3(2, 8, 64),  dim3(32, 8), 0, stream>>>(C0, ct0);
        transpose_nt<256><<<dim3(2, 8, 256), dim3(32, 8), 0, stream>>>(C1, ct1);
        transpose_nt<64> <<<dim3(2, 2, 256), dim3(32, 8), 0, stream>>>(C2, ct2);
        kan_mega2<<<1024, 256, 0, stream>>>(x, ct0, ct1, ct2, out);
    } else {
        kan_fused<<<NBATCH, 256, 0, stream>>>(x, C0, C1, C2, out);
    }
}

// Round 17
// 190.127 us; speedup vs baseline: 3.1411x; 1.1207x over previous
//
#include <hip/hip_runtime.h>

// KAN forward: 3 layers of [deg-3 B-spline basis (64 bases) -> einsum 'bik,ijk->bj'].
// Only 4 basis values are nonzero per point => 4-tap gather per (i,j).
//
// NUMERICS (frozen since R6 — absmax sits exactly at threshold; per-(b,j)
// product set and fp64 add order must stay bitwise-identical):
//  * knots: jnp.linspace fp32 semantics, endpoint forced to 1.0f
//  * basis: fp32 Cox-de Boor, reference expression tree, contraction OFF
//  * einsum: fp64 accumulation, per-(b,j) order = i ascending, k ascending
//  * skipping an i whose 4 weights are all +/-0 only removes exact +/-0.0
//    adds — IEEE-exact no-ops (validated R7-R16)
//
// PERF: R6 1967 -> R9 420 -> R14 371 -> R15 330 -> R16 213.  R16 analysis:
// mega2 138us (L1 46 request-floor + L2 ~14 + L3 ~7 VMEM, 61us VALU, badly
// overlapped: 41.5KB LDS -> 3 blocks/CU; dist-1 prefetch vs HBM-latency
// scattered loads; FETCH 200MB == 8 XCDs x tables = compulsory).  75us was
// transposes + 4 launch overheads.  R17: in-place compaction (LDS 41.5 ->
// 20.5KB -> 7 blocks/CU), dist-2 prefetch, single fused transpose dispatch.

#define NBATCH 4096

typedef float f4a __attribute__((ext_vector_type(4), aligned(4)));

// jnp.linspace(0,1,68,f32): delta = fl32(1/67); K[m] = fl32(m)*delta; K[67]=1.
__device__ __forceinline__ float knotf(int m) {
    if (m == 67) return 1.0f;
    return (float)m * (1.0f / 67.0f);
}

// Bitwise replica of the reference Cox-de Boor recursion on the 7-wide
// nonzero window around span t.  w[r] = B_{t-3+r,3}(x), r=0..3.
__device__ __forceinline__ void basis4(float xf, int& t_out, float w[4]) {
#pragma clang fp contract(off)
    int t = (int)floorf(xf * 67.0f);
    t = t < 0 ? 0 : (t > 66 ? 66 : t);
    #pragma unroll
    for (int it = 0; it < 2; ++it) {   // enforce K[t] <= x < K[t+1] on fp32 knots
        if (t > 0 && xf < knotf(t)) --t;
        else if (t < 66 && xf >= knotf(t + 1)) ++t;
    }
    float W[7];
    #pragma unroll
    for (int j = 0; j < 7; ++j) W[j] = 0.0f;
    W[3] = 1.0f;   // degree-0 indicator at span t
    #pragma unroll
    for (int d = 1; d <= 3; ++d) {
        #pragma unroll
        for (int j = 0; j <= 6 - d; ++j) {
            const int k = t - 3 + j;
            const float ka = knotf(k);
            const float kb = knotf(k + d);
            const float kc = knotf(k + d + 1);
            const float ke = knotf(k + 1);
            const float lt = ((xf - ka) / (kb - ka)) * W[j];
            const float rt = ((kc - xf) / (kc - ke)) * W[j + 1];
            W[j] = lt + rt;
        }
    }
    t_out = t;
    w[0] = W[0]; w[1] = W[1]; w[2] = W[2]; w[3] = W[3];
}

// Shift-aligned table entry: k0 = clamp(t-3,0,60); w'[m] applies to C[k0+m],
// m-ascending == k-ascending == R6 order; displaced/OOB slots get w'=0.
__device__ __forceinline__ void make_wk(float xf, float4& wv, int& kv) {
    float wp[4] = {0.f, 0.f, 0.f, 0.f};
    int k0 = 0;
    if (xf >= 0.0f && xf < 1.0f) {
        int t; float w[4];
        basis4(xf, t, w);
        k0 = t - 3;
        k0 = k0 < 0 ? 0 : (k0 > 60 ? 60 : k0);
        const int s = (t - 3) - k0;
        #pragma unroll
        for (int m = 0; m < 4; ++m) {
            const int r = m - s;
            wp[m] = (r >= 0 && r <= 3) ? w[r] : 0.0f;
        }
    }
    wv = make_float4(wp[0], wp[1], wp[2], wp[3]);
    kv = k0;
}

// ---------------- fused transpose: all three C[i][j][k] -> Ct[i][k][j] ------
__global__ void transpose_all(const float* __restrict__ C0, const float* __restrict__ C1,
                              const float* __restrict__ C2, float* __restrict__ Ct0,
                              float* __restrict__ Ct1, float* __restrict__ Ct2) {
    __shared__ float tile[32][33];
    const int z = blockIdx.z;
    const float* C; float* Ct; int OUT, i;
    if (z < 64)       { C = C0; Ct = Ct0; OUT = 256; i = z; }
    else if (z < 320) { C = C1; Ct = Ct1; OUT = 256; i = z - 64; }
    else              { C = C2; Ct = Ct2; OUT = 64;  i = z - 320;
                        if (blockIdx.y >= 2) return; }
    const int k0 = blockIdx.x * 32;
    const int j0 = blockIdx.y * 32;
    const float* src = C + (size_t)i * OUT * 64;
    #pragma unroll
    for (int r = threadIdx.y; r < 32; r += 8)
        tile[r][threadIdx.x] = src[(size_t)(j0 + r) * 64 + (k0 + threadIdx.x)];
    __syncthreads();
    float* dst = Ct + (size_t)i * 64 * OUT;
    #pragma unroll
    for (int r = threadIdx.y; r < 32; r += 8)
        dst[(size_t)(k0 + r) * OUT + (j0 + threadIdx.x)] = tile[threadIdx.x][r];
}

// ---------------- wave compaction, IN-PLACE ---------------------------------
// Entry order e ascending (= i ascending) preserved.  Write pos <= read index
// in every pass, and the wave reads all 64 entries of a pass (lockstep) before
// any write of that pass issues -> in-place is race-free.  Activity test
// treats -0.0 as zero; dropped entries' products are exact +/-0 no-op adds.
__device__ __forceinline__ int compact_wave(int lane, int passes,
        float4* __restrict__ wbuf, int* __restrict__ kbuf, int mult) {
    int base = 0;
    for (int p = 0; p < passes; ++p) {
        const int e = 64 * p + lane;
        const float4 wv = wbuf[e];
        const int    kv = kbuf[e];
        const bool act = (wv.x != 0.f) || (wv.y != 0.f) ||
                         (wv.z != 0.f) || (wv.w != 0.f);
        const unsigned long long mask = __ballot(act);
        const int pos = base + (int)__popcll(mask & ((1ull << lane) - 1ull));
        if (act) { wbuf[pos] = wv; kbuf[pos] = (e * 64 + kv) * mult; }
        base += (int)__popcll(mask);
    }
    return base;   // wave-uniform
}

// ---------------- gather over an active list (OUT=256 layers) ---------------
// Wave = one b; lane owns j-quad.  Per entry: wave-uniform row offset
// (readfirstlane -> SGPR addressing), 4x 1KB b128 row loads, 16 f64 FMA
// (entry-asc = i-asc, k-asc == R6 order), dist-2 prefetch (8 f4a in flight).
__device__ __forceinline__ void gather_list(const float* __restrict__ Ct,
        const float4* __restrict__ wl, const int* __restrict__ rl,
        int cnt, int j0, double acc[4]) {
    if (cnt <= 0) return;
    f4a c0[4], c1[4];
    {
        const int r0 = __builtin_amdgcn_readfirstlane(rl[0]);
        const float* p = Ct + r0 + j0;
        c0[0] = *(const f4a*)(p);       c0[1] = *(const f4a*)(p + 256);
        c0[2] = *(const f4a*)(p + 512); c0[3] = *(const f4a*)(p + 768);
    }
    {
        const int e1 = (cnt > 1) ? 1 : 0;
        const int r1 = __builtin_amdgcn_readfirstlane(rl[e1]);
        const float* p = Ct + r1 + j0;
        c1[0] = *(const f4a*)(p);       c1[1] = *(const f4a*)(p + 256);
        c1[2] = *(const f4a*)(p + 512); c1[3] = *(const f4a*)(p + 768);
    }
    for (int e = 0; e < cnt; ++e) {
        const int ep = (e + 2 < cnt) ? e + 2 : cnt - 1;
        const int rN = __builtin_amdgcn_readfirstlane(rl[ep]);
        f4a c2[4];
        {
            const float* p = Ct + rN + j0;
            c2[0] = *(const f4a*)(p);       c2[1] = *(const f4a*)(p + 256);
            c2[2] = *(const f4a*)(p + 512); c2[3] = *(const f4a*)(p + 768);
        }
        const float4 wv = wl[e];
        const double w0 = (double)wv.x, w1 = (double)wv.y;
        const double w2 = (double)wv.z, w3 = (double)wv.w;
        #pragma unroll
        for (int ee = 0; ee < 4; ++ee) {
            acc[ee] = fma(w0, (double)c0[0][ee], acc[ee]);   // k-ascending == R6
            acc[ee] = fma(w1, (double)c0[1][ee], acc[ee]);
            acc[ee] = fma(w2, (double)c0[2][ee], acc[ee]);
            acc[ee] = fma(w3, (double)c0[3][ee], acc[ee]);
        }
        #pragma unroll
        for (int r = 0; r < 4; ++r) { c0[r] = c1[r]; c1[r] = c2[r]; }
    }
}

// ---------------- mega kernel: all 3 layers, compacted L2/L3 ----------------
__global__ __launch_bounds__(256) void kan_mega3(
        const float* __restrict__ x,       // [4096][64]
        const float* __restrict__ Ct0,     // [64][64][256]
        const float* __restrict__ Ct1,     // [256][64][256]
        const float* __restrict__ Ct2,     // [256][64][64]
        float* __restrict__ out) {         // [4096][64]
    __shared__ __align__(16) float4 wtab[4][256];
    __shared__ int                  ktab[4][256];
    __shared__ int scnt[4];

    const int tid  = threadIdx.x;
    const int lane = tid & 63;
    const int wx   = tid >> 6;
    const int b    = blockIdx.x * 4 + wx;
    const int j0   = lane * 4;

    // ---- L1 table from x: 64 entries, all kept (x uniform in [0,1)) ----
    {
        float4 wv; int kv;
        make_wk(x[(size_t)b * 64 + lane], wv, kv);
        wtab[wx][lane] = wv;
        ktab[wx][lane] = (lane * 64 + kv) * 256;   // row offset directly
    }
    double acc1[4] = {0.0, 0.0, 0.0, 0.0};
    gather_list(Ct0, &wtab[wx][0], &ktab[wx][0], 64, j0, acc1);

    // ---- a1 rounding -> raw table -> in-place compacted L2 list ----
    #pragma unroll
    for (int e = 0; e < 4; ++e) {
        float4 wv; int kv;
        make_wk((float)acc1[e], wv, kv);   // same fp32 value as R16
        wtab[wx][j0 + e] = wv;
        ktab[wx][j0 + e] = kv;
    }
    const int cnt2 = compact_wave(lane, 4, &wtab[wx][0], &ktab[wx][0], 256);

    double acc2[4] = {0.0, 0.0, 0.0, 0.0};
    gather_list(Ct1, &wtab[wx][0], &ktab[wx][0], cnt2, j0, acc2);

    // ---- a2 rounding -> raw table -> in-place compacted L3 list ----
    #pragma unroll
    for (int e = 0; e < 4; ++e) {
        float4 wv; int kv;
        make_wk((float)acc2[e], wv, kv);
        wtab[wx][j0 + e] = wv;
        ktab[wx][j0 + e] = kv;
    }
    const int cnt3 = compact_wave(lane, 4, &wtab[wx][0], &ktab[wx][0], 64);
    if (lane == 0) scnt[wx] = cnt3;
    __syncthreads();
    if (wx != 0) return;

    // ---- layer 3 on wave 0: lane = (bsub, jq); 4-segment 1KB loads ----
    const int bsub = lane >> 4;
    const int jq   = lane & 15;
    const int cn   = scnt[bsub];
    const int cmax = max(max(scnt[0], scnt[1]), max(scnt[2], scnt[3]));
    double a3[4] = {0.0, 0.0, 0.0, 0.0};

    if (cmax > 0) {
        auto ldb = [&](int e, f4a p[4], float4& wv) {
            const int ec = (cn > 0) ? ((e < cn) ? e : cn - 1) : 0;
            wv = (cn > 0) ? wtab[bsub][ec] : make_float4(0.f, 0.f, 0.f, 0.f);
            int ro = (cn > 0) ? ktab[bsub][ec] : 0;
            if (e >= cn) wv = make_float4(0.f, 0.f, 0.f, 0.f);  // pad: exact no-op
            const float* pb = Ct2 + ro + jq * 4;
            p[0] = *(const f4a*)(pb);
            p[1] = *(const f4a*)(pb + 64);
            p[2] = *(const f4a*)(pb + 128);
            p[3] = *(const f4a*)(pb + 192);
        };
        f4a P0[4], P1[4]; float4 W0, W1;
        ldb(0, P0, W0);
        ldb(1, P1, W1);
        for (int e = 0; e < cmax; ++e) {
            f4a P2[4]; float4 W2;
            ldb(e + 2, P2, W2);
            const double w0 = (double)W0.x, w1 = (double)W0.y;
            const double w2 = (double)W0.z, w3 = (double)W0.w;
            #pragma unroll
            for (int ee = 0; ee < 4; ++ee) {
                a3[ee] = fma(w0, (double)P0[0][ee], a3[ee]);   // k-asc == R6
                a3[ee] = fma(w1, (double)P0[1][ee], a3[ee]);
                a3[ee] = fma(w2, (double)P0[2][ee], a3[ee]);
                a3[ee] = fma(w3, (double)P0[3][ee], a3[ee]);
            }
            #pragma unroll
            for (int r = 0; r < 4; ++r) { P0[r] = P1[r]; P1[r] = P2[r]; }
            W0 = W1; W1 = W2;
        }
    }

    const float4 o = make_float4((float)a3[0], (float)a3[1],
                                 (float)a3[2], (float)a3[3]);
    *(float4*)(out + (size_t)(blockIdx.x * 4 + bsub) * 64 + jq * 4) = o;
}

// ---------------- fallback: R6 monolithic (zero workspace, proven) ----------

__device__ __forceinline__ void stage1(float xf, float sw[4], int& st) {
    const bool inr = (xf >= 0.0f) && (xf < 1.0f);
    if (!inr) { st = -1; sw[0] = sw[1] = sw[2] = sw[3] = 0.0f; return; }
    int t; float w[4];
    basis4(xf, t, w);
    sw[0] = w[0]; sw[1] = w[1]; sw[2] = w[2]; sw[3] = w[3];
    st = t;
}

template<int IN, int OUT>
__device__ __forceinline__ float gather_acc(const float* __restrict__ C, int j,
                                            const float (*__restrict__ sw)[4],
                                            const int* __restrict__ st) {
    double acc = 0.0;
    for (int i = 0; i < IN; ++i) {
        const int t = st[i];
        if (t < 0) continue;
        const float* Crow = C + ((size_t)i * OUT + j) * 64;
        #pragma unroll
        for (int r = 0; r < 4; ++r) {
            const int k4 = t - 3 + r;
            if (k4 >= 0 && k4 <= 63)
                acc += (double)sw[i][r] * (double)Crow[k4];
        }
    }
    return (float)acc;
}

__global__ __launch_bounds__(256) void kan_fused(const float* __restrict__ x,
                                                 const float* __restrict__ C0,
                                                 const float* __restrict__ C1,
                                                 const float* __restrict__ C2,
                                                 float* __restrict__ out) {
    __shared__ float cur[256];
    __shared__ float sw[256][4];
    __shared__ int   st[256];
    const int b = blockIdx.x, tid = threadIdx.x;

    if (tid < 64) stage1(x[(size_t)b * 64 + tid], sw[tid], st[tid]);
    __syncthreads();
    {
        const float a = gather_acc<64, 256>(C0, tid, sw, st);
        __syncthreads();
        cur[tid] = a;
    }
    __syncthreads();

    stage1(cur[tid], sw[tid], st[tid]);
    __syncthreads();
    {
        const float a = gather_acc<256, 256>(C1, tid, sw, st);
        __syncthreads();
        cur[tid] = a;
    }
    __syncthreads();

    stage1(cur[tid], sw[tid], st[tid]);
    __syncthreads();
    if (tid < 64) out[(size_t)b * 64 + tid] = gather_acc<256, 64>(C2, tid, sw, st);
}

// ---------------- launcher --------------------------------------------------

extern "C" void kernel_launch(void* const* d_in, const int* in_sizes, int n_in,
                              void* d_out, int out_size, void* d_ws, size_t ws_size,
                              hipStream_t stream) {
    const float* x  = (const float*)d_in[0];   // (4096, 64)
    const float* C0 = (const float*)d_in[1];   // (64, 256, 64)
    const float* C1 = (const float*)d_in[2];   // (256, 256, 64)
    const float* C2 = (const float*)d_in[3];   // (256, 64, 64)
    float* out = (float*)d_out;                // (4096, 64)

    const size_t CT1 = (size_t)256 * 64 * 256 * 4;   // 16.78 MB
    const size_t CT0 = (size_t)64  * 64 * 256 * 4;   //  4.19 MB
    const size_t CT2 = (size_t)256 * 64 * 64  * 4;   //  4.19 MB
    const size_t need = CT1 + CT0 + CT2;             // 25.17 MB (R14-R16 proven)

    if (ws_size >= need) {
        float* ct1 = (float*)d_ws;
        float* ct0 = (float*)((char*)d_ws + CT1);
        float* ct2 = (float*)((char*)d_ws + CT1 + CT0);

        transpose_all<<<dim3(2, 8, 576), dim3(32, 8), 0, stream>>>(C0, C1, C2,
                                                                   ct0, ct1, ct2);
        kan_mega3<<<1024, 256, 0, stream>>>(x, ct0, ct1, ct2, out);
    } else {
        kan_fused<<<NBATCH, 256, 0, stream>>>(x, C0, C1, C2, out);
    }
}

// Round 18
// 185.741 us; speedup vs baseline: 3.2153x; 1.0236x over previous
//
#include <hip/hip_runtime.h>

// KAN forward: 3 layers of [deg-3 B-spline basis (64 bases) -> einsum 'bik,ijk->bj'].
// Only 4 basis values are nonzero per point => 4-tap gather per (i,j).
//
// NUMERICS (frozen since R6 — absmax sits exactly at threshold; per-(b,j)
// product set and fp64 add order must stay bitwise-identical):
//  * knots: jnp.linspace fp32 semantics, endpoint forced to 1.0f
//  * basis: fp32 Cox-de Boor, reference expression tree, contraction OFF
//  * einsum: fp64 accumulation, per-(b,j) order = i ascending, k ascending
//  * skipping an i whose 4 weights are all +/-0 only removes exact +/-0.0
//    adds — IEEE-exact no-ops (validated R7-R17)
//
// PERF: R6 1967 -> R9 420 -> R14 371 -> R15 330 -> R16 213 -> R17 190.
// R17 evidence: mega3 115.7us; the 74us gap did NOT shrink when dispatches
// went 4 -> 2 => gap is transpose_all execution (scalar 4B/lane, 128-256B
// wave requests ~ the R12 small-request pathology), not launch overhead.
// R18: transpose_fast — 64x64 tiles, float4 both sides (1KB/wave-instr in
// 4x256B segments), 64x65 LDS (2-way banks both phases, free), ~16x fewer
// instrs.  mega3 untouched (proven).

#define NBATCH 4096

typedef float f4a __attribute__((ext_vector_type(4), aligned(4)));

// jnp.linspace(0,1,68,f32): delta = fl32(1/67); K[m] = fl32(m)*delta; K[67]=1.
__device__ __forceinline__ float knotf(int m) {
    if (m == 67) return 1.0f;
    return (float)m * (1.0f / 67.0f);
}

// Bitwise replica of the reference Cox-de Boor recursion on the 7-wide
// nonzero window around span t.  w[r] = B_{t-3+r,3}(x), r=0..3.
__device__ __forceinline__ void basis4(float xf, int& t_out, float w[4]) {
#pragma clang fp contract(off)
    int t = (int)floorf(xf * 67.0f);
    t = t < 0 ? 0 : (t > 66 ? 66 : t);
    #pragma unroll
    for (int it = 0; it < 2; ++it) {   // enforce K[t] <= x < K[t+1] on fp32 knots
        if (t > 0 && xf < knotf(t)) --t;
        else if (t < 66 && xf >= knotf(t + 1)) ++t;
    }
    float W[7];
    #pragma unroll
    for (int j = 0; j < 7; ++j) W[j] = 0.0f;
    W[3] = 1.0f;   // degree-0 indicator at span t
    #pragma unroll
    for (int d = 1; d <= 3; ++d) {
        #pragma unroll
        for (int j = 0; j <= 6 - d; ++j) {
            const int k = t - 3 + j;
            const float ka = knotf(k);
            const float kb = knotf(k + d);
            const float kc = knotf(k + d + 1);
            const float ke = knotf(k + 1);
            const float lt = ((xf - ka) / (kb - ka)) * W[j];
            const float rt = ((kc - xf) / (kc - ke)) * W[j + 1];
            W[j] = lt + rt;
        }
    }
    t_out = t;
    w[0] = W[0]; w[1] = W[1]; w[2] = W[2]; w[3] = W[3];
}

// Shift-aligned table entry: k0 = clamp(t-3,0,60); w'[m] applies to C[k0+m],
// m-ascending == k-ascending == R6 order; displaced/OOB slots get w'=0.
__device__ __forceinline__ void make_wk(float xf, float4& wv, int& kv) {
    float wp[4] = {0.f, 0.f, 0.f, 0.f};
    int k0 = 0;
    if (xf >= 0.0f && xf < 1.0f) {
        int t; float w[4];
        basis4(xf, t, w);
        k0 = t - 3;
        k0 = k0 < 0 ? 0 : (k0 > 60 ? 60 : k0);
        const int s = (t - 3) - k0;
        #pragma unroll
        for (int m = 0; m < 4; ++m) {
            const int r = m - s;
            wp[m] = (r >= 0 && r <= 3) ? w[r] : 0.0f;
        }
    }
    wv = make_float4(wp[0], wp[1], wp[2], wp[3]);
    kv = k0;
}

// ---------------- fast fused transpose: C[i][j][k] -> Ct[i][k][j] -----------
// 64j x 64k tile per block.  Loads: lane=(jl,kq) -> float4 along k: wave = 4
// rows x 16 quads = 4 x 256B contiguous segments (1KB/instr).  Writes: lane=
// (kl,jq) -> float4 along j: same shape.  LDS 64x65: store addr (4kq+w)*65+jl
// == (4kq+jl+w) mod 32 -> 2-way; read addr k*65+4jq+w == (kl+4jq+w) mod 32
// -> 2-way.  Both free (m136).
__global__ __launch_bounds__(256) void transpose_fast(
        const float* __restrict__ C0, const float* __restrict__ C1,
        const float* __restrict__ C2, float* __restrict__ Ct0,
        float* __restrict__ Ct1, float* __restrict__ Ct2) {
    __shared__ float t[64][65];
    const int bid = blockIdx.x, tid = threadIdx.x;
    const float* C; float* Ct; int OUT, i, jt;
    if (bid < 256)       { C = C0; Ct = Ct0; OUT = 256; i = bid >> 2;          jt = bid & 3; }
    else if (bid < 1280) { C = C1; Ct = Ct1; OUT = 256; i = (bid - 256) >> 2;  jt = (bid - 256) & 3; }
    else                 { C = C2; Ct = Ct2; OUT = 64;  i = bid - 1280;        jt = 0; }
    const int j0 = jt * 64;
    const float* src = C + ((size_t)i * OUT + j0) * 64;
    float* dst = Ct + (size_t)i * 64 * OUT + j0;

    const int kq  = tid & 15;
    const int jl0 = tid >> 4;
    #pragma unroll
    for (int p = 0; p < 4; ++p) {
        const int jl = jl0 + 16 * p;
        const f4a v = *(const f4a*)(src + (size_t)jl * 64 + kq * 4);
        t[kq * 4 + 0][jl] = v[0];
        t[kq * 4 + 1][jl] = v[1];
        t[kq * 4 + 2][jl] = v[2];
        t[kq * 4 + 3][jl] = v[3];
    }
    __syncthreads();
    const int jq  = tid & 15;
    const int kl0 = tid >> 4;
    #pragma unroll
    for (int p = 0; p < 4; ++p) {
        const int k = kl0 + 16 * p;
        f4a o;
        o[0] = t[k][jq * 4 + 0];
        o[1] = t[k][jq * 4 + 1];
        o[2] = t[k][jq * 4 + 2];
        o[3] = t[k][jq * 4 + 3];
        *(f4a*)(dst + (size_t)k * OUT + jq * 4) = o;
    }
}

// ---------------- wave compaction, IN-PLACE ---------------------------------
// Entry order e ascending (= i ascending) preserved.  Write pos <= read index
// per pass; wave reads all 64 entries of a pass (lockstep) before writing ->
// race-free.  -0.0 counts as zero; dropped entries are exact no-op adds.
__device__ __forceinline__ int compact_wave(int lane, int passes,
        float4* __restrict__ wbuf, int* __restrict__ kbuf, int mult) {
    int base = 0;
    for (int p = 0; p < passes; ++p) {
        const int e = 64 * p + lane;
        const float4 wv = wbuf[e];
        const int    kv = kbuf[e];
        const bool act = (wv.x != 0.f) || (wv.y != 0.f) ||
                         (wv.z != 0.f) || (wv.w != 0.f);
        const unsigned long long mask = __ballot(act);
        const int pos = base + (int)__popcll(mask & ((1ull << lane) - 1ull));
        if (act) { wbuf[pos] = wv; kbuf[pos] = (e * 64 + kv) * mult; }
        base += (int)__popcll(mask);
    }
    return base;   // wave-uniform
}

// ---------------- gather over an active list (OUT=256 layers) ---------------
// Wave = one b; lane owns j-quad.  Per entry: wave-uniform row offset
// (readfirstlane -> SGPR addressing), 4x 1KB b128 row loads, 16 f64 FMA
// (entry-asc = i-asc, k-asc == R6 order), dist-2 prefetch (8 f4a in flight).
__device__ __forceinline__ void gather_list(const float* __restrict__ Ct,
        const float4* __restrict__ wl, const int* __restrict__ rl,
        int cnt, int j0, double acc[4]) {
    if (cnt <= 0) return;
    f4a c0[4], c1[4];
    {
        const int r0 = __builtin_amdgcn_readfirstlane(rl[0]);
        const float* p = Ct + r0 + j0;
        c0[0] = *(const f4a*)(p);       c0[1] = *(const f4a*)(p + 256);
        c0[2] = *(const f4a*)(p + 512); c0[3] = *(const f4a*)(p + 768);
    }
    {
        const int e1 = (cnt > 1) ? 1 : 0;
        const int r1 = __builtin_amdgcn_readfirstlane(rl[e1]);
        const float* p = Ct + r1 + j0;
        c1[0] = *(const f4a*)(p);       c1[1] = *(const f4a*)(p + 256);
        c1[2] = *(const f4a*)(p + 512); c1[3] = *(const f4a*)(p + 768);
    }
    for (int e = 0; e < cnt; ++e) {
        const int ep = (e + 2 < cnt) ? e + 2 : cnt - 1;
        const int rN = __builtin_amdgcn_readfirstlane(rl[ep]);
        f4a c2[4];
        {
            const float* p = Ct + rN + j0;
            c2[0] = *(const f4a*)(p);       c2[1] = *(const f4a*)(p + 256);
            c2[2] = *(const f4a*)(p + 512); c2[3] = *(const f4a*)(p + 768);
        }
        const float4 wv = wl[e];
        const double w0 = (double)wv.x, w1 = (double)wv.y;
        const double w2 = (double)wv.z, w3 = (double)wv.w;
        #pragma unroll
        for (int ee = 0; ee < 4; ++ee) {
            acc[ee] = fma(w0, (double)c0[0][ee], acc[ee]);   // k-ascending == R6
            acc[ee] = fma(w1, (double)c0[1][ee], acc[ee]);
            acc[ee] = fma(w2, (double)c0[2][ee], acc[ee]);
            acc[ee] = fma(w3, (double)c0[3][ee], acc[ee]);
        }
        #pragma unroll
        for (int r = 0; r < 4; ++r) { c0[r] = c1[r]; c1[r] = c2[r]; }
    }
}

// ---------------- mega kernel: all 3 layers, compacted L2/L3 ----------------
__global__ __launch_bounds__(256) void kan_mega3(
        const float* __restrict__ x,       // [4096][64]
        const float* __restrict__ Ct0,     // [64][64][256]
        const float* __restrict__ Ct1,     // [256][64][256]
        const float* __restrict__ Ct2,     // [256][64][64]
        float* __restrict__ out) {         // [4096][64]
    __shared__ __align__(16) float4 wtab[4][256];
    __shared__ int                  ktab[4][256];
    __shared__ int scnt[4];

    const int tid  = threadIdx.x;
    const int lane = tid & 63;
    const int wx   = tid >> 6;
    const int b    = blockIdx.x * 4 + wx;
    const int j0   = lane * 4;

    // ---- L1 table from x: 64 entries, all kept (x uniform in [0,1)) ----
    {
        float4 wv; int kv;
        make_wk(x[(size_t)b * 64 + lane], wv, kv);
        wtab[wx][lane] = wv;
        ktab[wx][lane] = (lane * 64 + kv) * 256;   // row offset directly
    }
    double acc1[4] = {0.0, 0.0, 0.0, 0.0};
    gather_list(Ct0, &wtab[wx][0], &ktab[wx][0], 64, j0, acc1);

    // ---- a1 rounding -> raw table -> in-place compacted L2 list ----
    #pragma unroll
    for (int e = 0; e < 4; ++e) {
        float4 wv; int kv;
        make_wk((float)acc1[e], wv, kv);   // same fp32 value as R17
        wtab[wx][j0 + e] = wv;
        ktab[wx][j0 + e] = kv;
    }
    const int cnt2 = compact_wave(lane, 4, &wtab[wx][0], &ktab[wx][0], 256);

    double acc2[4] = {0.0, 0.0, 0.0, 0.0};
    gather_list(Ct1, &wtab[wx][0], &ktab[wx][0], cnt2, j0, acc2);

    // ---- a2 rounding -> raw table -> in-place compacted L3 list ----
    #pragma unroll
    for (int e = 0; e < 4; ++e) {
        float4 wv; int kv;
        make_wk((float)acc2[e], wv, kv);
        wtab[wx][j0 + e] = wv;
        ktab[wx][j0 + e] = kv;
    }
    const int cnt3 = compact_wave(lane, 4, &wtab[wx][0], &ktab[wx][0], 64);
    if (lane == 0) scnt[wx] = cnt3;
    __syncthreads();
    if (wx != 0) return;

    // ---- layer 3 on wave 0: lane = (bsub, jq); 4-segment 1KB loads ----
    const int bsub = lane >> 4;
    const int jq   = lane & 15;
    const int cn   = scnt[bsub];
    const int cmax = max(max(scnt[0], scnt[1]), max(scnt[2], scnt[3]));
    double a3[4] = {0.0, 0.0, 0.0, 0.0};

    if (cmax > 0) {
        auto ldb = [&](int e, f4a p[4], float4& wv) {
            const int ec = (cn > 0) ? ((e < cn) ? e : cn - 1) : 0;
            wv = (cn > 0) ? wtab[bsub][ec] : make_float4(0.f, 0.f, 0.f, 0.f);
            int ro = (cn > 0) ? ktab[bsub][ec] : 0;
            if (e >= cn) wv = make_float4(0.f, 0.f, 0.f, 0.f);  // pad: exact no-op
            const float* pb = Ct2 + ro + jq * 4;
            p[0] = *(const f4a*)(pb);
            p[1] = *(const f4a*)(pb + 64);
            p[2] = *(const f4a*)(pb + 128);
            p[3] = *(const f4a*)(pb + 192);
        };
        f4a P0[4], P1[4]; float4 W0, W1;
        ldb(0, P0, W0);
        ldb(1, P1, W1);
        for (int e = 0; e < cmax; ++e) {
            f4a P2[4]; float4 W2;
            ldb(e + 2, P2, W2);
            const double w0 = (double)W0.x, w1 = (double)W0.y;
            const double w2 = (double)W0.z, w3 = (double)W0.w;
            #pragma unroll
            for (int ee = 0; ee < 4; ++ee) {
                a3[ee] = fma(w0, (double)P0[0][ee], a3[ee]);   // k-asc == R6
                a3[ee] = fma(w1, (double)P0[1][ee], a3[ee]);
                a3[ee] = fma(w2, (double)P0[2][ee], a3[ee]);
                a3[ee] = fma(w3, (double)P0[3][ee], a3[ee]);
            }
            #pragma unroll
            for (int r = 0; r < 4; ++r) { P0[r] = P1[r]; P1[r] = P2[r]; }
            W0 = W1; W1 = W2;
        }
    }

    const float4 o = make_float4((float)a3[0], (float)a3[1],
                                 (float)a3[2], (float)a3[3]);
    *(float4*)(out + (size_t)(blockIdx.x * 4 + bsub) * 64 + jq * 4) = o;
}

// ---------------- fallback: R6 monolithic (zero workspace, proven) ----------

__device__ __forceinline__ void stage1(float xf, float sw[4], int& st) {
    const bool inr = (xf >= 0.0f) && (xf < 1.0f);
    if (!inr) { st = -1; sw[0] = sw[1] = sw[2] = sw[3] = 0.0f; return; }
    int t; float w[4];
    basis4(xf, t, w);
    sw[0] = w[0]; sw[1] = w[1]; sw[2] = w[2]; sw[3] = w[3];
    st = t;
}

template<int IN, int OUT>
__device__ __forceinline__ float gather_acc(const float* __restrict__ C, int j,
                                            const float (*__restrict__ sw)[4],
                                            const int* __restrict__ st) {
    double acc = 0.0;
    for (int i = 0; i < IN; ++i) {
        const int t = st[i];
        if (t < 0) continue;
        const float* Crow = C + ((size_t)i * OUT + j) * 64;
        #pragma unroll
        for (int r = 0; r < 4; ++r) {
            const int k4 = t - 3 + r;
            if (k4 >= 0 && k4 <= 63)
                acc += (double)sw[i][r] * (double)Crow[k4];
        }
    }
    return (float)acc;
}

__global__ __launch_bounds__(256) void kan_fused(const float* __restrict__ x,
                                                 const float* __restrict__ C0,
                                                 const float* __restrict__ C1,
                                                 const float* __restrict__ C2,
                                                 float* __restrict__ out) {
    __shared__ float cur[256];
    __shared__ float sw[256][4];
    __shared__ int   st[256];
    const int b = blockIdx.x, tid = threadIdx.x;

    if (tid < 64) stage1(x[(size_t)b * 64 + tid], sw[tid], st[tid]);
    __syncthreads();
    {
        const float a = gather_acc<64, 256>(C0, tid, sw, st);
        __syncthreads();
        cur[tid] = a;
    }
    __syncthreads();

    stage1(cur[tid], sw[tid], st[tid]);
    __syncthreads();
    {
        const float a = gather_acc<256, 256>(C1, tid, sw, st);
        __syncthreads();
        cur[tid] = a;
    }
    __syncthreads();

    stage1(cur[tid], sw[tid], st[tid]);
    __syncthreads();
    if (tid < 64) out[(size_t)b * 64 + tid] = gather_acc<256, 64>(C2, tid, sw, st);
}

// ---------------- launcher --------------------------------------------------

extern "C" void kernel_launch(void* const* d_in, const int* in_sizes, int n_in,
                              void* d_out, int out_size, void* d_ws, size_t ws_size,
                              hipStream_t stream) {
    const float* x  = (const float*)d_in[0];   // (4096, 64)
    const float* C0 = (const float*)d_in[1];   // (64, 256, 64)
    const float* C1 = (const float*)d_in[2];   // (256, 256, 64)
    const float* C2 = (const float*)d_in[3];   // (256, 64, 64)
    float* out = (float*)d_out;                // (4096, 64)

    const size_t CT1 = (size_t)256 * 64 * 256 * 4;   // 16.78 MB
    const size_t CT0 = (size_t)64  * 64 * 256 * 4;   //  4.19 MB
    const size_t CT2 = (size_t)256 * 64 * 64  * 4;   //  4.19 MB
    const size_t need = CT1 + CT0 + CT2;             // 25.17 MB (R14-R17 proven)

    if (ws_size >= need) {
        float* ct1 = (float*)d_ws;
        float* ct0 = (float*)((char*)d_ws + CT1);
        float* ct2 = (float*)((char*)d_ws + CT1 + CT0);

        transpose_fast<<<1536, 256, 0, stream>>>(C0, C1, C2, ct0, ct1, ct2);
        kan_mega3<<<1024, 256, 0, stream>>>(x, ct0, ct1, ct2, out);
    } else {
        kan_fused<<<NBATCH, 256, 0, stream>>>(x, C0, C1, C2, out);
    }
}